// Round 5
// baseline (1342.888 us; speedup 1.0000x reference)
//
#include <hip/hip_runtime.h>
#include <math.h>

#define BB 4
#define TT 10
#define HH 96
#define WW 96
#define HWSZ 9216
#define LL 5

typedef _Float16 half8 __attribute__((ext_vector_type(8)));
typedef _Float16 half4 __attribute__((ext_vector_type(4)));
typedef float floatx4 __attribute__((ext_vector_type(4)));

// ---------------- prep: weights -> f16, MFMA-friendly [co][k] layouts ----------------
__global__ __launch_bounds__(256) void prep_weights(const float* __restrict__ i2f_w,
                                                    const float* __restrict__ h2f_w,
                                                    const float* __restrict__ i2h_w,
                                                    const float* __restrict__ ret_w,
                                                    const float* __restrict__ flows_w,
                                                    _Float16* __restrict__ wi16,
                                                    _Float16* __restrict__ wh16,
                                                    _Float16* __restrict__ wA16,
                                                    _Float16* __restrict__ rw16,
                                                    _Float16* __restrict__ fw16) {
    const int id = blockIdx.x * 256 + threadIdx.x;   // 0..287231
    if (id < 51200) {
        const int co = id / 1600, k = id % 1600, tap = k >> 6, ci = k & 63;
        wi16[id] = (_Float16)i2f_w[(co * 64 + ci) * 25 + tap];
    } else if (id < 102400) {
        const int r = id - 51200;
        const int co = r / 1600, k = r % 1600, tap = k >> 6, ci = k & 63;
        wh16[r] = (_Float16)h2f_w[(co * 64 + ci) * 25 + tap];
    } else if (id < 212992) {
        const int r = id - 102400;
        const int co = r / 576, k = r % 576, tap = k >> 6, ci = k & 63;
        wA16[r] = (_Float16)i2h_w[(co * 64 + ci) * 9 + tap];
    } else if (id < 274432) {
        const int r = id - 212992;
        rw16[r] = (_Float16)ret_w[r];   // already [co][320] with k = l*64+c
    } else {
        const int r = id - 274432;      // 0..12799
        const int co = r / 800, k = r % 800, tap = k >> 5, ci = k & 31;
        fw16[r] = (co < 10) ? (_Float16)flows_w[(co * 32 + ci) * 25 + tap] : (_Float16)0.0f;
    }
}

// ---------------- prep: x -> f16 channel-last x16[img][pos][ci], img flat (b*TT+t) ----
__global__ __launch_bounds__(256) void prep_x16(const float* __restrict__ x,
                                                _Float16* __restrict__ x16) {
    const int id = blockIdx.x * 256 + threadIdx.x;   // 0..368639
    const int img = id / HWSZ, pos = id % HWSZ;
    const float* src = x + (size_t)img * 64 * HWSZ + pos;
    _Float16* dst = x16 + ((size_t)img * HWSZ + pos) * 64;
    #pragma unroll
    for (int i = 0; i < 8; i++) {
        half8 v;
        #pragma unroll
        for (int j = 0; j < 8; j++)
            v[j] = (_Float16)src[(size_t)(i * 8 + j) * HWSZ];
        *(half8*)(dst + i * 8) = v;
    }
}

// ---------------- f1x: conv5x5(x_t) partials for ALL t, f32 out -----------------------
// Grid 5760 (g=t*4+b, 16x4 tile). Wave wv = output row y0+wv, FULL K (100 MFMA),
// no reduce, all waves store.
__global__ __launch_bounds__(256) void f1x_all(const _Float16* __restrict__ x16,
                                               const _Float16* __restrict__ wi16,
                                               float* __restrict__ f1x) {
    __shared__ _Float16 patch[160 * 64];            // 8x20 px, 20480 B
    const int tid = threadIdx.x;
    const int wv = tid >> 6, ln = tid & 63;
    const int lm = ln & 15, q = ln >> 4;
    const int g  = blockIdx.x / 144;                // t*4+b
    const int ti = blockIdx.x % 144;
    const int y0 = (ti / 6) * 4, x0 = (ti % 6) * 16;
    const int tt = g >> 2, b = g & 3;
    const _Float16* src = x16 + (size_t)(b * TT + tt) * HWSZ * 64;

    for (int m = tid; m < 1280; m += 256) {
        const int p = m >> 3, c = m & 7;
        const int pr = p / 20, pc = p % 20;
        const int gy = y0 - 2 + pr, gx = x0 - 2 + pc;
        half8 v = {};
        if (gy >= 0 && gy < HH && gx >= 0 && gx < WW)
            v = *(const half8*)(src + (size_t)(gy * WW + gx) * 64 + c * 8);
        *(half8*)(&patch[p * 64 + ((c * 8) ^ ((p & 7) << 3))]) = v;
    }
    __syncthreads();

    floatx4 acc[2] = {};
    for (int tap = 0; tap < 25; tap++) {
        const int ky = tap / 5, kx = tap % 5;
        const int p = (wv + ky) * 20 + lm + kx;
        const int sw = (p & 7) << 3;
        #pragma unroll
        for (int h = 0; h < 2; h++) {
            const int k0 = tap * 64 + h * 32;
            const half8 a0 = *(const half8*)(wi16 + (size_t)(0 * 16 + lm) * 1600 + k0 + q * 8);
            const half8 a1 = *(const half8*)(wi16 + (size_t)(1 * 16 + lm) * 1600 + k0 + q * 8);
            const half8 bf = *(const half8*)(&patch[p * 64 + ((h * 32 + q * 8) ^ sw)]);
            acc[0] = __builtin_amdgcn_mfma_f32_16x16x32_f16(a0, bf, acc[0], 0, 0, 0);
            acc[1] = __builtin_amdgcn_mfma_f32_16x16x32_f16(a1, bf, acc[1], 0, 0, 0);
        }
    }
    const int pos = (y0 + wv) * WW + x0 + lm;
    float* op = f1x + ((size_t)g * HWSZ + pos) * 32;
    *(floatx4*)(op + q * 4)      = acc[0];
    *(floatx4*)(op + 16 + q * 4) = acc[1];
}

// ---------------- f1h: tanh(conv5x5(h) + f1x + biases), 16x2 tile, grid 1152 ----------
// Wave = (row nn=wv>>1, m-tile mh=wv&1), FULL K (50 MFMA), no reduce, all waves store.
__global__ __launch_bounds__(256) void f1h_mfma(const _Float16* __restrict__ h16p,
                                                const _Float16* __restrict__ wh16,
                                                const float* __restrict__ f1x,
                                                const float* __restrict__ bi,
                                                const float* __restrict__ bh,
                                                _Float16* __restrict__ f116, int t) {
    __shared__ _Float16 patch[120 * 64];            // 6x20 px, 15360 B
    const int tid = threadIdx.x;
    const int wv = tid >> 6, ln = tid & 63;
    const int lm = ln & 15, q = ln >> 4;
    const int b  = blockIdx.x / 288;
    const int ti = blockIdx.x % 288;
    const int y0 = (ti / 6) * 2, x0 = (ti % 6) * 16;
    const _Float16* src = h16p + (size_t)b * HWSZ * 64;

    for (int m = tid; m < 960; m += 256) {
        const int p = m >> 3, c = m & 7;
        const int pr = p / 20, pc = p % 20;
        const int gy = y0 - 2 + pr, gx = x0 - 2 + pc;
        half8 v = {};
        if (gy >= 0 && gy < HH && gx >= 0 && gx < WW)
            v = *(const half8*)(src + (size_t)(gy * WW + gx) * 64 + c * 8);
        *(half8*)(&patch[p * 64 + ((c * 8) ^ ((p & 7) << 3))]) = v;
    }
    __syncthreads();

    const int nn = wv >> 1, mh = wv & 1;
    floatx4 acc = {};
    for (int tap = 0; tap < 25; tap++) {
        const int ky = tap / 5, kx = tap % 5;
        const int p = (nn + ky) * 20 + lm + kx;
        const int sw = (p & 7) << 3;
        #pragma unroll
        for (int h = 0; h < 2; h++) {
            const half8 a = *(const half8*)(wh16 + (size_t)(mh * 16 + lm) * 1600
                                            + tap * 64 + h * 32 + q * 8);
            const half8 bf = *(const half8*)(&patch[p * 64 + ((h * 32 + q * 8) ^ sw)]);
            acc = __builtin_amdgcn_mfma_f32_16x16x32_f16(a, bf, acc, 0, 0, 0);
        }
    }
    const int pos = (y0 + nn) * WW + x0 + lm;
    const float* vx = f1x + ((size_t)(t * BB + b) * HWSZ + pos) * 32 + mh * 16;
    const floatx4 xv = *(const floatx4*)(vx + q * 4);
    half4 pk;
    #pragma unroll
    for (int r = 0; r < 4; r++)
        pk[r] = (_Float16)tanhf(acc[r] + xv[r] + bi[mh * 16 + q * 4 + r]
                                               + bh[mh * 16 + q * 4 + r]);
    *(half4*)(f116 + ((size_t)b * HWSZ + pos) * 32 + mh * 16 + q * 4) = pk;
}

// ---------------- gate_mega: flows conv + warp-gather + i2h(3x3) + h2h(1x1) + GRU -----
// Grid 768; block = 16x3 tile. hp prefetched at top; flows wave computes bilinear
// coeffs in-register (no flw[] hop, one fewer barrier). 3 syncs total.
__global__ __launch_bounds__(256) void gate_mega(const _Float16* __restrict__ x16,
                                                 const _Float16* __restrict__ wA16,
                                                 const float* __restrict__ i2h_b,
                                                 const _Float16* __restrict__ h16p,
                                                 const _Float16* __restrict__ f116,
                                                 const _Float16* __restrict__ fw16,
                                                 const float* __restrict__ flows_b,
                                                 const _Float16* __restrict__ rw16,
                                                 const float* __restrict__ ret_b,
                                                 float* __restrict__ outs,
                                                 float* __restrict__ last_h,
                                                 _Float16* __restrict__ h16c, int t) {
    __shared__ _Float16 xp[90 * 64];                // 11520 B, 5x18 x-patch
    __shared__ __align__(16) _Float16 uni[48 * 320];// 30720 B: f1 patch then warped tile
    __shared__ int   goff[240][4];                  // 3840 B
    __shared__ float gwgt[240][4];                  // 3840 B
    const int tid = threadIdx.x;
    const int wv = tid >> 6, ln = tid & 63;
    const int lm = ln & 15, q = ln >> 4;
    const int b  = blockIdx.x / 192;
    const int ti = blockIdx.x % 192;
    const int y0 = (ti / 6) * 3, x0 = (ti % 6) * 16;

    // phase -1: prefetch prev-h (consumed only in epilogue; hides HBM latency)
    float hp[3][4];
    #pragma unroll
    for (int nn = 0; nn < 3; nn++) {
        const int pos = (y0 + nn) * WW + x0 + lm;
        #pragma unroll
        for (int r = 0; r < 4; r++) {
            const int c = wv * 16 + q * 4 + r;
            hp[nn][r] = (t > 0) ? outs[(((size_t)b * TT + (t - 1)) * 64 + c) * HWSZ + pos] : 0.0f;
        }
    }

    // phase 0a: x patch rows y0-1..y0+3, cols x0-1..x0+16 (image remap quirk: t*4+b)
    const _Float16* xb = x16 + (size_t)(t * BB + b) * HWSZ * 64;
    for (int m = tid; m < 720; m += 256) {
        const int p = m >> 3, c = m & 7;
        const int pr = p / 18, pc = p % 18;
        const int gy = y0 - 1 + pr, gx = x0 - 1 + pc;
        half8 v = {};
        if (gy >= 0 && gy < HH && gx >= 0 && gx < WW)
            v = *(const half8*)(xb + (size_t)(gy * WW + gx) * 64 + c * 8);
        *(half8*)(&xp[p * 64 + ((c * 8) ^ ((p & 7) << 3))]) = v;
    }
    // phase 0b: f1 patch rows y0-2..y0+4, cols x0-2..x0+17, stride 40 halfs
    const _Float16* fb = f116 + (size_t)b * HWSZ * 32;
    for (int m = tid; m < 560; m += 256) {
        const int p = m >> 2, c = m & 3;
        const int pr = p / 20, pc = p % 20;
        const int gy = y0 - 2 + pr, gx = x0 - 2 + pc;
        half8 v = {};
        if (gy >= 0 && gy < HH && gx >= 0 && gx < WW)
            v = *(const half8*)(fb + (size_t)(gy * WW + gx) * 32 + c * 8);
        *(half8*)(&uni[p * 40 + c * 8]) = v;
    }
    __syncthreads();

    // phase 1: flows conv5x5 + in-register bilinear coeffs. wave rr<3 owns row y0+rr.
    if (wv < 3) {
        floatx4 fa = {};
        for (int tap = 0; tap < 25; tap++) {
            const int ky = tap / 5, kx = tap % 5;
            const half8 af = *(const half8*)(fw16 + (size_t)lm * 800 + tap * 32 + q * 8);
            const int p = (wv + ky) * 20 + lm + kx;
            const half8 bf = *(const half8*)(&uni[p * 40 + q * 8]);
            fa = __builtin_amdgcn_mfma_f32_16x16x32_f16(af, bf, fa, 0, 0, 0);
        }
        // lane (lm,q) holds flow channels 4q..4q+3 = pairs for l in {2q, 2q+1}
        #pragma unroll
        for (int l2 = 0; l2 < 2; l2++) {
            const int l = q * 2 + l2;
            if (l < LL) {
                const float f0  = -(fa[2 * l2 + 0] + flows_b[q * 4 + 2 * l2 + 0]);
                const float f1v = -(fa[2 * l2 + 1] + flows_b[q * 4 + 2 * l2 + 1]);
                const int yg = y0 + wv, xg = x0 + lm;
                const float nx = 2.0f * ((float)xg + f0)  / (float)(WW - 1) - 1.0f;
                const float ny = 2.0f * ((float)yg + f1v) / (float)(HH - 1) - 1.0f;
                const float fx = (nx + 1.0f) * (WW * 0.5f) - 0.5f;
                const float fy = (ny + 1.0f) * (HH * 0.5f) - 0.5f;
                const float x0f = floorf(fx), y0f = floorf(fy);
                const float wx = fx - x0f, wy = fy - y0f;
                const int xi0 = (int)x0f, yi0 = (int)y0f;
                const int idx = (wv * 16 + lm) * 5 + l;
                #pragma unroll
                for (int k = 0; k < 4; k++) {
                    const int yi = yi0 + (k >> 1);
                    const int xi = xi0 + (k & 1);
                    const bool ok = (xi >= 0 && xi < WW && yi >= 0 && yi < HH);
                    const int yc = min(max(yi, 0), HH - 1);
                    const int xc = min(max(xi, 0), WW - 1);
                    goff[idx][k] = yc * WW + xc;
                    const float wk = ((k & 1) ? wx : 1.0f - wx) * ((k >> 1) ? wy : 1.0f - wy);
                    gwgt[idx][k] = ok ? wk : 0.0f;
                }
            }
        }
    }
    __syncthreads();

    // phase 2: gather warped tile [pos48][l*64+ch] into uni (f1 patch now dead)
    const _Float16* hb = h16p + (size_t)b * HWSZ * 64;
    for (int m = tid; m < 1920; m += 256) {
        const int pl = m >> 3, c = m & 7;
        const int pp = pl / 5, l = pl % 5;
        const half8 v0 = *(const half8*)(hb + (size_t)goff[pl][0] * 64 + c * 8);
        const half8 v1 = *(const half8*)(hb + (size_t)goff[pl][1] * 64 + c * 8);
        const half8 v2 = *(const half8*)(hb + (size_t)goff[pl][2] * 64 + c * 8);
        const half8 v3 = *(const half8*)(hb + (size_t)goff[pl][3] * 64 + c * 8);
        const float w0 = gwgt[pl][0], w1 = gwgt[pl][1], w2 = gwgt[pl][2], w3 = gwgt[pl][3];
        half8 o;
        #pragma unroll
        for (int j = 0; j < 8; j++)
            o[j] = (_Float16)((float)v0[j] * w0 + (float)v1[j] * w1
                            + (float)v2[j] * w2 + (float)v3[j] * w3);
        *(half8*)(&uni[pp * 320 + ((l * 64 + c * 8) ^ ((pp & 7) << 3))]) = o;
    }
    __syncthreads();

    // phase 3: main MFMA
    floatx4 aR[3], aU[3], aIM[3], aHM[3];
    #pragma unroll
    for (int nn = 0; nn < 3; nn++)
        #pragma unroll
        for (int r = 0; r < 4; r++) {
            const int c = wv * 16 + q * 4 + r;
            aR[nn][r]  = i2h_b[c]      + ret_b[c];
            aU[nn][r]  = i2h_b[64 + c] + ret_b[64 + c];
            aIM[nn][r] = i2h_b[128 + c];
            aHM[nn][r] = ret_b[128 + c];
        }

    // i2h 3x3 (K=576) from x patch
    for (int tap = 0; tap < 9; tap++) {
        const int ky = tap / 3, kx = tap % 3;
        #pragma unroll
        for (int h = 0; h < 2; h++) {
            const int k0 = tap * 64 + h * 32;
            const half8 ar = *(const half8*)(wA16 + (size_t)((wv + 0) * 16 + lm) * 576 + k0 + q * 8);
            const half8 au = *(const half8*)(wA16 + (size_t)((wv + 4) * 16 + lm) * 576 + k0 + q * 8);
            const half8 am = *(const half8*)(wA16 + (size_t)((wv + 8) * 16 + lm) * 576 + k0 + q * 8);
            #pragma unroll
            for (int nn = 0; nn < 3; nn++) {
                const int p = (nn + ky) * 18 + lm + kx;
                const int sw = (p & 7) << 3;
                const half8 bf = *(const half8*)(&xp[p * 64 + ((h * 32 + q * 8) ^ sw)]);
                aR[nn]  = __builtin_amdgcn_mfma_f32_16x16x32_f16(ar, bf, aR[nn],  0, 0, 0);
                aU[nn]  = __builtin_amdgcn_mfma_f32_16x16x32_f16(au, bf, aU[nn],  0, 0, 0);
                aIM[nn] = __builtin_amdgcn_mfma_f32_16x16x32_f16(am, bf, aIM[nn], 0, 0, 0);
            }
        }
    }
    // h2h 1x1 (K=320) from warped LDS tile
    for (int s = 0; s < 10; s++) {
        const int k0 = s * 32;
        const half8 ar = *(const half8*)(rw16 + (size_t)((wv + 0) * 16 + lm) * 320 + k0 + q * 8);
        const half8 au = *(const half8*)(rw16 + (size_t)((wv + 4) * 16 + lm) * 320 + k0 + q * 8);
        const half8 am = *(const half8*)(rw16 + (size_t)((wv + 8) * 16 + lm) * 320 + k0 + q * 8);
        #pragma unroll
        for (int nn = 0; nn < 3; nn++) {
            const half8 bf = *(const half8*)(&uni[(nn * 16 + lm) * 320 + ((k0 + q * 8) ^ ((lm & 7) << 3))]);
            aR[nn]  = __builtin_amdgcn_mfma_f32_16x16x32_f16(ar, bf, aR[nn],  0, 0, 0);
            aU[nn]  = __builtin_amdgcn_mfma_f32_16x16x32_f16(au, bf, aU[nn],  0, 0, 0);
            aHM[nn] = __builtin_amdgcn_mfma_f32_16x16x32_f16(am, bf, aHM[nn], 0, 0, 0);
        }
    }

    // epilogue: GRU gates
    #pragma unroll
    for (int nn = 0; nn < 3; nn++) {
        const int pos = (y0 + nn) * WW + x0 + lm;
        half4 pk;
        #pragma unroll
        for (int r = 0; r < 4; r++) {
            const int c = wv * 16 + q * 4 + r;
            const float rg = 1.0f / (1.0f + expf(-aR[nn][r]));
            const float ug = 1.0f / (1.0f + expf(-aU[nn][r]));
            const float mg = tanhf(aIM[nn][r] + rg * aHM[nn][r]);
            const float nh = ug * hp[nn][r] + (1.0f - ug) * mg;
            outs[(((size_t)b * TT + t) * 64 + c) * HWSZ + pos] = nh;
            if (t == TT - 1) last_h[((size_t)b * 64 + c) * HWSZ + pos] = nh;
            pk[r] = (_Float16)nh;
        }
        *(half4*)(h16c + ((size_t)b * HWSZ + pos) * 64 + wv * 16 + q * 4) = pk;
    }
}

extern "C" void kernel_launch(void* const* d_in, const int* in_sizes, int n_in,
                              void* d_out, int out_size, void* d_ws, size_t ws_size,
                              hipStream_t stream) {
    const float* inputs  = (const float*)d_in[0];
    const float* i2h_w   = (const float*)d_in[1];
    const float* i2h_b   = (const float*)d_in[2];
    const float* i2f_w   = (const float*)d_in[3];
    const float* i2f_b   = (const float*)d_in[4];
    const float* h2f_w   = (const float*)d_in[5];
    const float* h2f_b   = (const float*)d_in[6];
    const float* flows_w = (const float*)d_in[7];
    const float* flows_b = (const float*)d_in[8];
    const float* ret_w   = (const float*)d_in[9];
    const float* ret_b   = (const float*)d_in[10];

    float* out = (float*)d_out;

    // workspace layout (bytes), total ~106.8 MB
    char* base = (char*)d_ws;
    _Float16* h16    = (_Float16*)base;   base += 9437184;    // 2 x (4*9216*64) f16 dbuf
    _Float16* f116   = (_Float16*)base;   base += 2359296;    // 4*9216*32 f16
    _Float16* x16    = (_Float16*)base;   base += 47185920;   // 40*9216*64 f16
    float*    f1x    = (float*)base;      base += 47185920;   // 40*9216*32 f32
    _Float16* wi16   = (_Float16*)base;   base += 102400;     // 32*1600
    _Float16* wh16   = (_Float16*)base;   base += 102400;
    _Float16* wA16   = (_Float16*)base;   base += 221184;     // 192*576
    _Float16* rw16   = (_Float16*)base;   base += 122880;     // 192*320
    _Float16* fw16   = (_Float16*)base;   base += 25600;      // 16*800

    float* outs   = out;
    float* last_h = out + (size_t)BB * TT * 64 * HWSZ;

    hipMemsetAsync(h16, 0, 4718592, stream);   // buffer 0 = h at t=0

    prep_weights<<<1122, 256, 0, stream>>>(i2f_w, h2f_w, i2h_w, ret_w, flows_w,
                                           wi16, wh16, wA16, rw16, fw16);
    prep_x16<<<1440, 256, 0, stream>>>(inputs, x16);
    f1x_all<<<5760, 256, 0, stream>>>(x16, wi16, f1x);

    const size_t HB = (size_t)BB * HWSZ * 64;   // elements per h16 buffer
    for (int t = 0; t < TT; t++) {
        _Float16* hprev = h16 + (size_t)(t & 1) * HB;
        _Float16* hcur  = h16 + (size_t)((t + 1) & 1) * HB;
        f1h_mfma<<<1152, 256, 0, stream>>>(hprev, wh16, f1x, i2f_b, h2f_b, f116, t);
        gate_mega<<<768, 256, 0, stream>>>(x16, wA16, i2h_b, hprev, f116, fw16, flows_b,
                                           rw16, ret_b, outs, last_h, hcur, t);
    }
}

// Round 6
// 1049.153 us; speedup vs baseline: 1.2800x; 1.2800x over previous
//
#include <hip/hip_runtime.h>
#include <math.h>

#define BB 4
#define TT 10
#define HH 96
#define WW 96
#define HWSZ 9216
#define LL 5

typedef _Float16 half8 __attribute__((ext_vector_type(8)));
typedef _Float16 half4 __attribute__((ext_vector_type(4)));
typedef float floatx4 __attribute__((ext_vector_type(4)));

// ---------------- prep: weights -> f16, MFMA-friendly [co][k] layouts ----------------
__global__ __launch_bounds__(256) void prep_weights(const float* __restrict__ i2f_w,
                                                    const float* __restrict__ h2f_w,
                                                    const float* __restrict__ i2h_w,
                                                    const float* __restrict__ ret_w,
                                                    const float* __restrict__ flows_w,
                                                    _Float16* __restrict__ wi16,
                                                    _Float16* __restrict__ wh16,
                                                    _Float16* __restrict__ wA16,
                                                    _Float16* __restrict__ rw16,
                                                    _Float16* __restrict__ fw16) {
    const int id = blockIdx.x * 256 + threadIdx.x;   // 0..287231
    if (id < 51200) {
        const int co = id / 1600, k = id % 1600, tap = k >> 6, ci = k & 63;
        wi16[id] = (_Float16)i2f_w[(co * 64 + ci) * 25 + tap];
    } else if (id < 102400) {
        const int r = id - 51200;
        const int co = r / 1600, k = r % 1600, tap = k >> 6, ci = k & 63;
        wh16[r] = (_Float16)h2f_w[(co * 64 + ci) * 25 + tap];
    } else if (id < 212992) {
        const int r = id - 102400;
        const int co = r / 576, k = r % 576, tap = k >> 6, ci = k & 63;
        wA16[r] = (_Float16)i2h_w[(co * 64 + ci) * 9 + tap];
    } else if (id < 274432) {
        const int r = id - 212992;
        rw16[r] = (_Float16)ret_w[r];   // already [co][320] with k = l*64+c
    } else {
        const int r = id - 274432;      // 0..12799
        const int co = r / 800, k = r % 800, tap = k >> 5, ci = k & 31;
        fw16[r] = (co < 10) ? (_Float16)flows_w[(co * 32 + ci) * 25 + tap] : (_Float16)0.0f;
    }
}

// ---------------- prep: x -> f16 channel-last x16[img][pos][ci], img flat (b*TT+t) ----
__global__ __launch_bounds__(256) void prep_x16(const float* __restrict__ x,
                                                _Float16* __restrict__ x16) {
    const int id = blockIdx.x * 256 + threadIdx.x;   // 0..368639
    const int img = id / HWSZ, pos = id % HWSZ;
    const float* src = x + (size_t)img * 64 * HWSZ + pos;
    _Float16* dst = x16 + ((size_t)img * HWSZ + pos) * 64;
    #pragma unroll
    for (int i = 0; i < 8; i++) {
        half8 v;
        #pragma unroll
        for (int j = 0; j < 8; j++)
            v[j] = (_Float16)src[(size_t)(i * 8 + j) * HWSZ];
        *(half8*)(dst + i * 8) = v;
    }
}

// ---------------- f1x: conv5x5(x_t) partials for ALL t, f32 out -----------------------
// Grid 5760 (g=t*4+b, 16x4 tile). Wave split = (tap-half, ci-half) [R4: amortizes
// weight gathers over 4 rows]. Epilogue: ALL waves write partials, ALL 256 threads
// reduce + store (thread (wv,ln) -> row y0+wv).
__global__ __launch_bounds__(256) void f1x_all(const _Float16* __restrict__ x16,
                                               const _Float16* __restrict__ wi16,
                                               float* __restrict__ f1x) {
    __shared__ __align__(16) char smraw[33792];     // max(patch 20480, red 4*64*33*4)
    _Float16* patch = (_Float16*)smraw;
    float* red = (float*)smraw;                     // [(w*64+ln)*33 + slot]
    const int tid = threadIdx.x;
    const int wv = tid >> 6, ln = tid & 63;
    const int lm = ln & 15, q = ln >> 4;
    const int g  = blockIdx.x / 144;                // t*4+b
    const int ti = blockIdx.x % 144;
    const int y0 = (ti / 6) * 4, x0 = (ti % 6) * 16;
    const int tt = g >> 2, b = g & 3;
    const _Float16* src = x16 + (size_t)(b * TT + tt) * HWSZ * 64;

    for (int m = tid; m < 1280; m += 256) {
        const int p = m >> 3, c = m & 7;
        const int pr = p / 20, pc = p % 20;
        const int gy = y0 - 2 + pr, gx = x0 - 2 + pc;
        half8 v = {};
        if (gy >= 0 && gy < HH && gx >= 0 && gx < WW)
            v = *(const half8*)(src + (size_t)(gy * WW + gx) * 64 + c * 8);
        *(half8*)(&patch[p * 64 + ((c * 8) ^ ((p & 7) << 3))]) = v;
    }
    __syncthreads();

    const int ci0 = (wv & 1) * 32;
    const int tp0 = (wv >> 1) ? 13 : 0, tp1 = (wv >> 1) ? 25 : 13;
    floatx4 acc[4][2] = {};
    for (int tap = tp0; tap < tp1; tap++) {
        const int ky = tap / 5, kx = tap % 5;
        const half8 a0 = *(const half8*)(wi16 + (size_t)(0 * 16 + lm) * 1600 + tap * 64 + ci0 + q * 8);
        const half8 a1 = *(const half8*)(wi16 + (size_t)(1 * 16 + lm) * 1600 + tap * 64 + ci0 + q * 8);
        #pragma unroll
        for (int n = 0; n < 4; n++) {
            const int p = (n + ky) * 20 + lm + kx;
            const half8 bf = *(const half8*)(&patch[p * 64 + ((ci0 + q * 8) ^ ((p & 7) << 3))]);
            acc[n][0] = __builtin_amdgcn_mfma_f32_16x16x32_f16(a0, bf, acc[n][0], 0, 0, 0);
            acc[n][1] = __builtin_amdgcn_mfma_f32_16x16x32_f16(a1, bf, acc[n][1], 0, 0, 0);
        }
    }
    __syncthreads();                                // patch reads done; smraw reusable
    #pragma unroll
    for (int n = 0; n < 4; n++)
        #pragma unroll
        for (int mt = 0; mt < 2; mt++)
            #pragma unroll
            for (int r = 0; r < 4; r++)
                red[(wv * 64 + ln) * 33 + n * 8 + mt * 4 + r] = acc[n][mt][r];
    __syncthreads();
    // thread (wv,ln): row y0+wv, slots wv*8+j (j<8): mt=j>>2, r=j&3. Sum w0+w1+w2+w3.
    float o[8];
    #pragma unroll
    for (int j = 0; j < 8; j++) {
        const int s = wv * 8 + j;
        o[j] = red[(0 * 64 + ln) * 33 + s] + red[(1 * 64 + ln) * 33 + s]
             + red[(2 * 64 + ln) * 33 + s] + red[(3 * 64 + ln) * 33 + s];
    }
    const int pos = (y0 + wv) * WW + x0 + lm;
    float* op = f1x + ((size_t)g * HWSZ + pos) * 32;
    *(floatx4*)(op + q * 4)      = floatx4{o[0], o[1], o[2], o[3]};
    *(floatx4*)(op + 16 + q * 4) = floatx4{o[4], o[5], o[6], o[7]};
}

// ---------------- f1h: tanh(conv5x5(h) + f1x + biases), 16x2 tile, grid 1152 ----------
// Wave split = (tap-half, ci-half); all-thread reduce + store epilogue.
__global__ __launch_bounds__(256) void f1h_mfma(const _Float16* __restrict__ h16p,
                                                const _Float16* __restrict__ wh16,
                                                const float* __restrict__ f1x,
                                                const float* __restrict__ bi,
                                                const float* __restrict__ bh,
                                                _Float16* __restrict__ f116, int t) {
    __shared__ __align__(16) char smraw[17408];     // max(patch 15360, red 4*64*17*4)
    _Float16* patch = (_Float16*)smraw;
    float* red = (float*)smraw;                     // [(w*64+ln)*17 + slot]
    const int tid = threadIdx.x;
    const int wv = tid >> 6, ln = tid & 63;
    const int lm = ln & 15, q = ln >> 4;
    const int b  = blockIdx.x / 288;
    const int ti = blockIdx.x % 288;
    const int y0 = (ti / 6) * 2, x0 = (ti % 6) * 16;
    const _Float16* src = h16p + (size_t)b * HWSZ * 64;

    for (int m = tid; m < 960; m += 256) {
        const int p = m >> 3, c = m & 7;
        const int pr = p / 20, pc = p % 20;
        const int gy = y0 - 2 + pr, gx = x0 - 2 + pc;
        half8 v = {};
        if (gy >= 0 && gy < HH && gx >= 0 && gx < WW)
            v = *(const half8*)(src + (size_t)(gy * WW + gx) * 64 + c * 8);
        *(half8*)(&patch[p * 64 + ((c * 8) ^ ((p & 7) << 3))]) = v;
    }
    __syncthreads();

    const int ci0 = (wv & 1) * 32;
    const int tp0 = (wv >> 1) ? 13 : 0, tp1 = (wv >> 1) ? 25 : 13;
    floatx4 acc[2][2] = {};
    for (int tap = tp0; tap < tp1; tap++) {
        const int ky = tap / 5, kx = tap % 5;
        const half8 a0 = *(const half8*)(wh16 + (size_t)(0 * 16 + lm) * 1600 + tap * 64 + ci0 + q * 8);
        const half8 a1 = *(const half8*)(wh16 + (size_t)(1 * 16 + lm) * 1600 + tap * 64 + ci0 + q * 8);
        #pragma unroll
        for (int n = 0; n < 2; n++) {
            const int p = (n + ky) * 20 + lm + kx;
            const half8 bf = *(const half8*)(&patch[p * 64 + ((ci0 + q * 8) ^ ((p & 7) << 3))]);
            acc[n][0] = __builtin_amdgcn_mfma_f32_16x16x32_f16(a0, bf, acc[n][0], 0, 0, 0);
            acc[n][1] = __builtin_amdgcn_mfma_f32_16x16x32_f16(a1, bf, acc[n][1], 0, 0, 0);
        }
    }
    __syncthreads();
    #pragma unroll
    for (int n = 0; n < 2; n++)
        #pragma unroll
        for (int mt = 0; mt < 2; mt++)
            #pragma unroll
            for (int r = 0; r < 4; r++)
                red[(wv * 64 + ln) * 17 + n * 8 + mt * 4 + r] = acc[n][mt][r];
    __syncthreads();
    // thread (wv,ln): nn=wv>>1, mh=wv&1, slots wv*4+j (j<4, r=j)
    float o[4];
    #pragma unroll
    for (int j = 0; j < 4; j++) {
        const int s = wv * 4 + j;
        o[j] = red[(0 * 64 + ln) * 17 + s] + red[(1 * 64 + ln) * 17 + s]
             + red[(2 * 64 + ln) * 17 + s] + red[(3 * 64 + ln) * 17 + s];
    }
    const int nn = wv >> 1, mh = wv & 1;
    const int pos = (y0 + nn) * WW + x0 + lm;
    const float* vx = f1x + ((size_t)(t * BB + b) * HWSZ + pos) * 32 + mh * 16;
    half4 pk;
    #pragma unroll
    for (int r = 0; r < 4; r++)
        pk[r] = (_Float16)tanhf(o[r] + vx[q * 4 + r] + bi[mh * 16 + q * 4 + r]
                                                     + bh[mh * 16 + q * 4 + r]);
    *(half4*)(f116 + ((size_t)b * HWSZ + pos) * 32 + mh * 16 + q * 4) = pk;
}

// ---------------- gate_mega: flows conv + warp-gather + i2h(3x3) + h2h(1x1) + GRU -----
// Grid 768; block = 16x3 tile. hp prefetched at top; flows wave computes bilinear
// coeffs in-register. 3 syncs total.
__global__ __launch_bounds__(256) void gate_mega(const _Float16* __restrict__ x16,
                                                 const _Float16* __restrict__ wA16,
                                                 const float* __restrict__ i2h_b,
                                                 const _Float16* __restrict__ h16p,
                                                 const _Float16* __restrict__ f116,
                                                 const _Float16* __restrict__ fw16,
                                                 const float* __restrict__ flows_b,
                                                 const _Float16* __restrict__ rw16,
                                                 const float* __restrict__ ret_b,
                                                 float* __restrict__ outs,
                                                 float* __restrict__ last_h,
                                                 _Float16* __restrict__ h16c, int t) {
    __shared__ _Float16 xp[90 * 64];                // 11520 B, 5x18 x-patch
    __shared__ __align__(16) _Float16 uni[48 * 320];// 30720 B: f1 patch then warped tile
    __shared__ int   goff[240][4];                  // 3840 B
    __shared__ float gwgt[240][4];                  // 3840 B
    const int tid = threadIdx.x;
    const int wv = tid >> 6, ln = tid & 63;
    const int lm = ln & 15, q = ln >> 4;
    const int b  = blockIdx.x / 192;
    const int ti = blockIdx.x % 192;
    const int y0 = (ti / 6) * 3, x0 = (ti % 6) * 16;

    // phase -1: prefetch prev-h (consumed only in epilogue; hides HBM latency)
    float hp[3][4];
    #pragma unroll
    for (int nn = 0; nn < 3; nn++) {
        const int pos = (y0 + nn) * WW + x0 + lm;
        #pragma unroll
        for (int r = 0; r < 4; r++) {
            const int c = wv * 16 + q * 4 + r;
            hp[nn][r] = (t > 0) ? outs[(((size_t)b * TT + (t - 1)) * 64 + c) * HWSZ + pos] : 0.0f;
        }
    }

    // phase 0a: x patch rows y0-1..y0+3, cols x0-1..x0+16 (image remap quirk: t*4+b)
    const _Float16* xb = x16 + (size_t)(t * BB + b) * HWSZ * 64;
    for (int m = tid; m < 720; m += 256) {
        const int p = m >> 3, c = m & 7;
        const int pr = p / 18, pc = p % 18;
        const int gy = y0 - 1 + pr, gx = x0 - 1 + pc;
        half8 v = {};
        if (gy >= 0 && gy < HH && gx >= 0 && gx < WW)
            v = *(const half8*)(xb + (size_t)(gy * WW + gx) * 64 + c * 8);
        *(half8*)(&xp[p * 64 + ((c * 8) ^ ((p & 7) << 3))]) = v;
    }
    // phase 0b: f1 patch rows y0-2..y0+4, cols x0-2..x0+17, stride 40 halfs
    const _Float16* fb = f116 + (size_t)b * HWSZ * 32;
    for (int m = tid; m < 560; m += 256) {
        const int p = m >> 2, c = m & 3;
        const int pr = p / 20, pc = p % 20;
        const int gy = y0 - 2 + pr, gx = x0 - 2 + pc;
        half8 v = {};
        if (gy >= 0 && gy < HH && gx >= 0 && gx < WW)
            v = *(const half8*)(fb + (size_t)(gy * WW + gx) * 32 + c * 8);
        *(half8*)(&uni[p * 40 + c * 8]) = v;
    }
    __syncthreads();

    // phase 1: flows conv5x5 + in-register bilinear coeffs. wave rr<3 owns row y0+rr.
    if (wv < 3) {
        floatx4 fa = {};
        for (int tap = 0; tap < 25; tap++) {
            const int ky = tap / 5, kx = tap % 5;
            const half8 af = *(const half8*)(fw16 + (size_t)lm * 800 + tap * 32 + q * 8);
            const int p = (wv + ky) * 20 + lm + kx;
            const half8 bf = *(const half8*)(&uni[p * 40 + q * 8]);
            fa = __builtin_amdgcn_mfma_f32_16x16x32_f16(af, bf, fa, 0, 0, 0);
        }
        // lane (lm,q) holds flow channels 4q..4q+3 = pairs for l in {2q, 2q+1}
        #pragma unroll
        for (int l2 = 0; l2 < 2; l2++) {
            const int l = q * 2 + l2;
            if (l < LL) {
                const float f0  = -(fa[2 * l2 + 0] + flows_b[q * 4 + 2 * l2 + 0]);
                const float f1v = -(fa[2 * l2 + 1] + flows_b[q * 4 + 2 * l2 + 1]);
                const int yg = y0 + wv, xg = x0 + lm;
                const float nx = 2.0f * ((float)xg + f0)  / (float)(WW - 1) - 1.0f;
                const float ny = 2.0f * ((float)yg + f1v) / (float)(HH - 1) - 1.0f;
                const float fx = (nx + 1.0f) * (WW * 0.5f) - 0.5f;
                const float fy = (ny + 1.0f) * (HH * 0.5f) - 0.5f;
                const float x0f = floorf(fx), y0f = floorf(fy);
                const float wx = fx - x0f, wy = fy - y0f;
                const int xi0 = (int)x0f, yi0 = (int)y0f;
                const int idx = (wv * 16 + lm) * 5 + l;
                #pragma unroll
                for (int k = 0; k < 4; k++) {
                    const int yi = yi0 + (k >> 1);
                    const int xi = xi0 + (k & 1);
                    const bool ok = (xi >= 0 && xi < WW && yi >= 0 && yi < HH);
                    const int yc = min(max(yi, 0), HH - 1);
                    const int xc = min(max(xi, 0), WW - 1);
                    goff[idx][k] = yc * WW + xc;
                    const float wk = ((k & 1) ? wx : 1.0f - wx) * ((k >> 1) ? wy : 1.0f - wy);
                    gwgt[idx][k] = ok ? wk : 0.0f;
                }
            }
        }
    }
    __syncthreads();

    // phase 2: gather warped tile [pos48][l*64+ch] into uni (f1 patch now dead)
    const _Float16* hb = h16p + (size_t)b * HWSZ * 64;
    for (int m = tid; m < 1920; m += 256) {
        const int pl = m >> 3, c = m & 7;
        const int pp = pl / 5, l = pl % 5;
        const half8 v0 = *(const half8*)(hb + (size_t)goff[pl][0] * 64 + c * 8);
        const half8 v1 = *(const half8*)(hb + (size_t)goff[pl][1] * 64 + c * 8);
        const half8 v2 = *(const half8*)(hb + (size_t)goff[pl][2] * 64 + c * 8);
        const half8 v3 = *(const half8*)(hb + (size_t)goff[pl][3] * 64 + c * 8);
        const float w0 = gwgt[pl][0], w1 = gwgt[pl][1], w2 = gwgt[pl][2], w3 = gwgt[pl][3];
        half8 o;
        #pragma unroll
        for (int j = 0; j < 8; j++)
            o[j] = (_Float16)((float)v0[j] * w0 + (float)v1[j] * w1
                            + (float)v2[j] * w2 + (float)v3[j] * w3);
        *(half8*)(&uni[pp * 320 + ((l * 64 + c * 8) ^ ((pp & 7) << 3))]) = o;
    }
    __syncthreads();

    // phase 3: main MFMA
    floatx4 aR[3], aU[3], aIM[3], aHM[3];
    #pragma unroll
    for (int nn = 0; nn < 3; nn++)
        #pragma unroll
        for (int r = 0; r < 4; r++) {
            const int c = wv * 16 + q * 4 + r;
            aR[nn][r]  = i2h_b[c]      + ret_b[c];
            aU[nn][r]  = i2h_b[64 + c] + ret_b[64 + c];
            aIM[nn][r] = i2h_b[128 + c];
            aHM[nn][r] = ret_b[128 + c];
        }

    // i2h 3x3 (K=576) from x patch
    for (int tap = 0; tap < 9; tap++) {
        const int ky = tap / 3, kx = tap % 3;
        #pragma unroll
        for (int h = 0; h < 2; h++) {
            const int k0 = tap * 64 + h * 32;
            const half8 ar = *(const half8*)(wA16 + (size_t)((wv + 0) * 16 + lm) * 576 + k0 + q * 8);
            const half8 au = *(const half8*)(wA16 + (size_t)((wv + 4) * 16 + lm) * 576 + k0 + q * 8);
            const half8 am = *(const half8*)(wA16 + (size_t)((wv + 8) * 16 + lm) * 576 + k0 + q * 8);
            #pragma unroll
            for (int nn = 0; nn < 3; nn++) {
                const int p = (nn + ky) * 18 + lm + kx;
                const int sw = (p & 7) << 3;
                const half8 bf = *(const half8*)(&xp[p * 64 + ((h * 32 + q * 8) ^ sw)]);
                aR[nn]  = __builtin_amdgcn_mfma_f32_16x16x32_f16(ar, bf, aR[nn],  0, 0, 0);
                aU[nn]  = __builtin_amdgcn_mfma_f32_16x16x32_f16(au, bf, aU[nn],  0, 0, 0);
                aIM[nn] = __builtin_amdgcn_mfma_f32_16x16x32_f16(am, bf, aIM[nn], 0, 0, 0);
            }
        }
    }
    // h2h 1x1 (K=320) from warped LDS tile
    for (int s = 0; s < 10; s++) {
        const int k0 = s * 32;
        const half8 ar = *(const half8*)(rw16 + (size_t)((wv + 0) * 16 + lm) * 320 + k0 + q * 8);
        const half8 au = *(const half8*)(rw16 + (size_t)((wv + 4) * 16 + lm) * 320 + k0 + q * 8);
        const half8 am = *(const half8*)(rw16 + (size_t)((wv + 8) * 16 + lm) * 320 + k0 + q * 8);
        #pragma unroll
        for (int nn = 0; nn < 3; nn++) {
            const half8 bf = *(const half8*)(&uni[(nn * 16 + lm) * 320 + ((k0 + q * 8) ^ ((lm & 7) << 3))]);
            aR[nn]  = __builtin_amdgcn_mfma_f32_16x16x32_f16(ar, bf, aR[nn],  0, 0, 0);
            aU[nn]  = __builtin_amdgcn_mfma_f32_16x16x32_f16(au, bf, aU[nn],  0, 0, 0);
            aHM[nn] = __builtin_amdgcn_mfma_f32_16x16x32_f16(am, bf, aHM[nn], 0, 0, 0);
        }
    }

    // epilogue: GRU gates
    #pragma unroll
    for (int nn = 0; nn < 3; nn++) {
        const int pos = (y0 + nn) * WW + x0 + lm;
        half4 pk;
        #pragma unroll
        for (int r = 0; r < 4; r++) {
            const int c = wv * 16 + q * 4 + r;
            const float rg = 1.0f / (1.0f + expf(-aR[nn][r]));
            const float ug = 1.0f / (1.0f + expf(-aU[nn][r]));
            const float mg = tanhf(aIM[nn][r] + rg * aHM[nn][r]);
            const float nh = ug * hp[nn][r] + (1.0f - ug) * mg;
            outs[(((size_t)b * TT + t) * 64 + c) * HWSZ + pos] = nh;
            if (t == TT - 1) last_h[((size_t)b * 64 + c) * HWSZ + pos] = nh;
            pk[r] = (_Float16)nh;
        }
        *(half4*)(h16c + ((size_t)b * HWSZ + pos) * 64 + wv * 16 + q * 4) = pk;
    }
}

extern "C" void kernel_launch(void* const* d_in, const int* in_sizes, int n_in,
                              void* d_out, int out_size, void* d_ws, size_t ws_size,
                              hipStream_t stream) {
    const float* inputs  = (const float*)d_in[0];
    const float* i2h_w   = (const float*)d_in[1];
    const float* i2h_b   = (const float*)d_in[2];
    const float* i2f_w   = (const float*)d_in[3];
    const float* i2f_b   = (const float*)d_in[4];
    const float* h2f_w   = (const float*)d_in[5];
    const float* h2f_b   = (const float*)d_in[6];
    const float* flows_w = (const float*)d_in[7];
    const float* flows_b = (const float*)d_in[8];
    const float* ret_w   = (const float*)d_in[9];
    const float* ret_b   = (const float*)d_in[10];

    float* out = (float*)d_out;

    // workspace layout (bytes), total ~106.8 MB
    char* base = (char*)d_ws;
    _Float16* h16    = (_Float16*)base;   base += 9437184;    // 2 x (4*9216*64) f16 dbuf
    _Float16* f116   = (_Float16*)base;   base += 2359296;    // 4*9216*32 f16
    _Float16* x16    = (_Float16*)base;   base += 47185920;   // 40*9216*64 f16
    float*    f1x    = (float*)base;      base += 47185920;   // 40*9216*32 f32
    _Float16* wi16   = (_Float16*)base;   base += 102400;     // 32*1600
    _Float16* wh16   = (_Float16*)base;   base += 102400;
    _Float16* wA16   = (_Float16*)base;   base += 221184;     // 192*576
    _Float16* rw16   = (_Float16*)base;   base += 122880;     // 192*320
    _Float16* fw16   = (_Float16*)base;   base += 25600;      // 16*800

    float* outs   = out;
    float* last_h = out + (size_t)BB * TT * 64 * HWSZ;

    hipMemsetAsync(h16, 0, 4718592, stream);   // buffer 0 = h at t=0

    prep_weights<<<1122, 256, 0, stream>>>(i2f_w, h2f_w, i2h_w, ret_w, flows_w,
                                           wi16, wh16, wA16, rw16, fw16);
    prep_x16<<<1440, 256, 0, stream>>>(inputs, x16);
    f1x_all<<<5760, 256, 0, stream>>>(x16, wi16, f1x);

    const size_t HB = (size_t)BB * HWSZ * 64;   // elements per h16 buffer
    for (int t = 0; t < TT; t++) {
        _Float16* hprev = h16 + (size_t)(t & 1) * HB;
        _Float16* hcur  = h16 + (size_t)((t + 1) & 1) * HB;
        f1h_mfma<<<1152, 256, 0, stream>>>(hprev, wh16, f1x, i2f_b, h2f_b, f116, t);
        gate_mega<<<768, 256, 0, stream>>>(x16, wA16, i2h_b, hprev, f116, fw16, flows_b,
                                           rw16, ret_b, outs, last_h, hcur, t);
    }
}

// Round 7
// 844.602 us; speedup vs baseline: 1.5900x; 1.2422x over previous
//
#include <hip/hip_runtime.h>
#include <math.h>

#define BB 4
#define TT 10
#define HH 96
#define WW 96
#define HWSZ 9216
#define LL 5

typedef _Float16 half8 __attribute__((ext_vector_type(8)));
typedef _Float16 half4 __attribute__((ext_vector_type(4)));
typedef float floatx4 __attribute__((ext_vector_type(4)));

// ---------------- prep: weights -> f16, FRAGMENT-PACKED layouts -----------------------
// All A-operands stored as [frag][lane64][8]: lane ln holds A[row=ln&15][k0+(ln>>4)*8+j]
// so a wave's fragment load is ONE contiguous 1KB burst (coalesced, 4 cache lines).
// wi16/wh16: frag = (mt<2, tap<25, h<2)   -> off = ((mt*25+tap)*2+h)*512 + ln*8
// wA16:      frag = (mt<12, tap<9, h<2)   -> off = ((mt*9+tap)*2+h)*512 + ln*8
// rw16:      frag = (mt<12, s<10)         -> off = (mt*10+s)*512 + ln*8
// fw16:      frag = (tap<25)              -> off = tap*512 + ln*8   (co<10 live)
__global__ __launch_bounds__(256) void prep_weights(const float* __restrict__ i2f_w,
                                                    const float* __restrict__ h2f_w,
                                                    const float* __restrict__ i2h_w,
                                                    const float* __restrict__ ret_w,
                                                    const float* __restrict__ flows_w,
                                                    _Float16* __restrict__ wi16,
                                                    _Float16* __restrict__ wh16,
                                                    _Float16* __restrict__ wA16,
                                                    _Float16* __restrict__ rw16,
                                                    _Float16* __restrict__ fw16) {
    const int id = blockIdx.x * 256 + threadIdx.x;   // 0..287231
    if (id < 102400) {                               // wi16 / wh16 (5x5, 64ch, M=32)
        const int seg = id / 51200;                  // 0: wi16, 1: wh16
        const int r = id % 51200;
        const int mt = r / 25600, r2 = r % 25600;
        const int tap = r2 / 1024, r3 = r2 % 1024;
        const int h = r3 >> 9, ln = (r3 >> 3) & 63, j = r3 & 7;
        const int co = mt * 16 + (ln & 15);
        const int ci = h * 32 + ((ln >> 4) & 3) * 8 + j;
        const float v = seg ? h2f_w[(co * 64 + ci) * 25 + tap]
                            : i2f_w[(co * 64 + ci) * 25 + tap];
        (seg ? wh16 : wi16)[r] = (_Float16)v;
    } else if (id < 212992) {                        // wA16 (3x3, 64ch, M=192)
        const int r = id - 102400;                   // 0..110591
        const int mt = r / 9216, r2 = r % 9216;
        const int tap = r2 / 1024, r3 = r2 % 1024;
        const int h = r3 >> 9, ln = (r3 >> 3) & 63, j = r3 & 7;
        const int co = mt * 16 + (ln & 15);
        const int ci = h * 32 + ((ln >> 4) & 3) * 8 + j;
        wA16[r] = (_Float16)i2h_w[(co * 64 + ci) * 9 + tap];
    } else if (id < 274432) {                        // rw16 (1x1, K=320, M=192)
        const int r = id - 212992;                   // 0..61439
        const int mt = r / 5120, r2 = r % 5120;
        const int s = r2 / 512, r3 = r2 % 512;
        const int ln = r3 >> 3, j = r3 & 7;
        const int co = mt * 16 + (ln & 15);
        const int k = s * 32 + ((ln >> 4) & 3) * 8 + j;
        rw16[r] = (_Float16)ret_w[co * 320 + k];
    } else {                                         // fw16 (5x5, 32ch, M=16, 10 live)
        const int r = id - 274432;                   // 0..12799
        const int tap = r / 512, r3 = r % 512;
        const int ln = r3 >> 3, j = r3 & 7;
        const int co = ln & 15;
        const int ci = ((ln >> 4) & 3) * 8 + j;
        fw16[r] = (co < 10) ? (_Float16)flows_w[(co * 32 + ci) * 25 + tap] : (_Float16)0.0f;
    }
}

// ---------------- prep: x -> f16 channel-last x16[img][pos][ci], img flat (b*TT+t) ----
__global__ __launch_bounds__(256) void prep_x16(const float* __restrict__ x,
                                                _Float16* __restrict__ x16) {
    const int id = blockIdx.x * 256 + threadIdx.x;   // 0..368639
    const int img = id / HWSZ, pos = id % HWSZ;
    const float* src = x + (size_t)img * 64 * HWSZ + pos;
    _Float16* dst = x16 + ((size_t)img * HWSZ + pos) * 64;
    #pragma unroll
    for (int i = 0; i < 8; i++) {
        half8 v;
        #pragma unroll
        for (int j = 0; j < 8; j++)
            v[j] = (_Float16)src[(size_t)(i * 8 + j) * HWSZ];
        *(half8*)(dst + i * 8) = v;
    }
}

// ---------------- f1x: conv5x5(x_t) partials for ALL t, f32 out -----------------------
// Grid 5760 (g=t*4+b, 16x4 tile). Wave split = (tap-half, ci-half). All-thread
// reduce + store epilogue. Weight loads: packed fragments (coalesced 1KB).
__global__ __launch_bounds__(256) void f1x_all(const _Float16* __restrict__ x16,
                                               const _Float16* __restrict__ wi16,
                                               float* __restrict__ f1x) {
    __shared__ __align__(16) char smraw[33792];     // max(patch 20480, red 4*64*33*4)
    _Float16* patch = (_Float16*)smraw;
    float* red = (float*)smraw;                     // [(w*64+ln)*33 + slot]
    const int tid = threadIdx.x;
    const int wv = tid >> 6, ln = tid & 63;
    const int lm = ln & 15, q = ln >> 4;
    const int g  = blockIdx.x / 144;                // t*4+b
    const int ti = blockIdx.x % 144;
    const int y0 = (ti / 6) * 4, x0 = (ti % 6) * 16;
    const int tt = g >> 2, b = g & 3;
    const _Float16* src = x16 + (size_t)(b * TT + tt) * HWSZ * 64;

    for (int m = tid; m < 1280; m += 256) {
        const int p = m >> 3, c = m & 7;
        const int pr = p / 20, pc = p % 20;
        const int gy = y0 - 2 + pr, gx = x0 - 2 + pc;
        half8 v = {};
        if (gy >= 0 && gy < HH && gx >= 0 && gx < WW)
            v = *(const half8*)(src + (size_t)(gy * WW + gx) * 64 + c * 8);
        *(half8*)(&patch[p * 64 + ((c * 8) ^ ((p & 7) << 3))]) = v;
    }
    __syncthreads();

    const int hh = wv & 1;                          // ci-half
    const int ci0 = hh * 32;
    const int tp0 = (wv >> 1) ? 13 : 0, tp1 = (wv >> 1) ? 25 : 13;
    floatx4 acc[4][2] = {};
    for (int tap = tp0; tap < tp1; tap++) {
        const int ky = tap / 5, kx = tap % 5;
        const half8 a0 = *(const half8*)(wi16 + (size_t)((0 * 25 + tap) * 2 + hh) * 512 + ln * 8);
        const half8 a1 = *(const half8*)(wi16 + (size_t)((1 * 25 + tap) * 2 + hh) * 512 + ln * 8);
        #pragma unroll
        for (int n = 0; n < 4; n++) {
            const int p = (n + ky) * 20 + lm + kx;
            const half8 bf = *(const half8*)(&patch[p * 64 + ((ci0 + q * 8) ^ ((p & 7) << 3))]);
            acc[n][0] = __builtin_amdgcn_mfma_f32_16x16x32_f16(a0, bf, acc[n][0], 0, 0, 0);
            acc[n][1] = __builtin_amdgcn_mfma_f32_16x16x32_f16(a1, bf, acc[n][1], 0, 0, 0);
        }
    }
    __syncthreads();                                // patch reads done; smraw reusable
    #pragma unroll
    for (int n = 0; n < 4; n++)
        #pragma unroll
        for (int mt = 0; mt < 2; mt++)
            #pragma unroll
            for (int r = 0; r < 4; r++)
                red[(wv * 64 + ln) * 33 + n * 8 + mt * 4 + r] = acc[n][mt][r];
    __syncthreads();
    float o[8];
    #pragma unroll
    for (int j = 0; j < 8; j++) {
        const int s = wv * 8 + j;
        o[j] = red[(0 * 64 + ln) * 33 + s] + red[(1 * 64 + ln) * 33 + s]
             + red[(2 * 64 + ln) * 33 + s] + red[(3 * 64 + ln) * 33 + s];
    }
    const int pos = (y0 + wv) * WW + x0 + lm;
    float* op = f1x + ((size_t)g * HWSZ + pos) * 32;
    *(floatx4*)(op + q * 4)      = floatx4{o[0], o[1], o[2], o[3]};
    *(floatx4*)(op + 16 + q * 4) = floatx4{o[4], o[5], o[6], o[7]};
}

// ---------------- f1h: tanh(conv5x5(h) + f1x + biases), 16x2 tile, grid 1152 ----------
__global__ __launch_bounds__(256) void f1h_mfma(const _Float16* __restrict__ h16p,
                                                const _Float16* __restrict__ wh16,
                                                const float* __restrict__ f1x,
                                                const float* __restrict__ bi,
                                                const float* __restrict__ bh,
                                                _Float16* __restrict__ f116, int t) {
    __shared__ __align__(16) char smraw[17408];     // max(patch 15360, red 4*64*17*4)
    _Float16* patch = (_Float16*)smraw;
    float* red = (float*)smraw;                     // [(w*64+ln)*17 + slot]
    const int tid = threadIdx.x;
    const int wv = tid >> 6, ln = tid & 63;
    const int lm = ln & 15, q = ln >> 4;
    const int b  = blockIdx.x / 288;
    const int ti = blockIdx.x % 288;
    const int y0 = (ti / 6) * 2, x0 = (ti % 6) * 16;
    const _Float16* src = h16p + (size_t)b * HWSZ * 64;

    for (int m = tid; m < 960; m += 256) {
        const int p = m >> 3, c = m & 7;
        const int pr = p / 20, pc = p % 20;
        const int gy = y0 - 2 + pr, gx = x0 - 2 + pc;
        half8 v = {};
        if (gy >= 0 && gy < HH && gx >= 0 && gx < WW)
            v = *(const half8*)(src + (size_t)(gy * WW + gx) * 64 + c * 8);
        *(half8*)(&patch[p * 64 + ((c * 8) ^ ((p & 7) << 3))]) = v;
    }
    __syncthreads();

    const int hh = wv & 1;
    const int ci0 = hh * 32;
    const int tp0 = (wv >> 1) ? 13 : 0, tp1 = (wv >> 1) ? 25 : 13;
    floatx4 acc[2][2] = {};
    for (int tap = tp0; tap < tp1; tap++) {
        const int ky = tap / 5, kx = tap % 5;
        const half8 a0 = *(const half8*)(wh16 + (size_t)((0 * 25 + tap) * 2 + hh) * 512 + ln * 8);
        const half8 a1 = *(const half8*)(wh16 + (size_t)((1 * 25 + tap) * 2 + hh) * 512 + ln * 8);
        #pragma unroll
        for (int n = 0; n < 2; n++) {
            const int p = (n + ky) * 20 + lm + kx;
            const half8 bf = *(const half8*)(&patch[p * 64 + ((ci0 + q * 8) ^ ((p & 7) << 3))]);
            acc[n][0] = __builtin_amdgcn_mfma_f32_16x16x32_f16(a0, bf, acc[n][0], 0, 0, 0);
            acc[n][1] = __builtin_amdgcn_mfma_f32_16x16x32_f16(a1, bf, acc[n][1], 0, 0, 0);
        }
    }
    __syncthreads();
    #pragma unroll
    for (int n = 0; n < 2; n++)
        #pragma unroll
        for (int mt = 0; mt < 2; mt++)
            #pragma unroll
            for (int r = 0; r < 4; r++)
                red[(wv * 64 + ln) * 17 + n * 8 + mt * 4 + r] = acc[n][mt][r];
    __syncthreads();
    float o[4];
    #pragma unroll
    for (int j = 0; j < 4; j++) {
        const int s = wv * 4 + j;
        o[j] = red[(0 * 64 + ln) * 17 + s] + red[(1 * 64 + ln) * 17 + s]
             + red[(2 * 64 + ln) * 17 + s] + red[(3 * 64 + ln) * 17 + s];
    }
    const int nn = wv >> 1, mh = wv & 1;
    const int pos = (y0 + nn) * WW + x0 + lm;
    const float* vx = f1x + ((size_t)(t * BB + b) * HWSZ + pos) * 32 + mh * 16;
    half4 pk;
    #pragma unroll
    for (int r = 0; r < 4; r++)
        pk[r] = (_Float16)tanhf(o[r] + vx[q * 4 + r] + bi[mh * 16 + q * 4 + r]
                                                     + bh[mh * 16 + q * 4 + r]);
    *(half4*)(f116 + ((size_t)b * HWSZ + pos) * 32 + mh * 16 + q * 4) = pk;
}

// ---------------- gate_mega: flows conv + warp-gather + i2h(3x3) + h2h(1x1) + GRU -----
// Grid 768; block = 16x3 tile. Packed weight fragments throughout.
__global__ __launch_bounds__(256) void gate_mega(const _Float16* __restrict__ x16,
                                                 const _Float16* __restrict__ wA16,
                                                 const float* __restrict__ i2h_b,
                                                 const _Float16* __restrict__ h16p,
                                                 const _Float16* __restrict__ f116,
                                                 const _Float16* __restrict__ fw16,
                                                 const float* __restrict__ flows_b,
                                                 const _Float16* __restrict__ rw16,
                                                 const float* __restrict__ ret_b,
                                                 float* __restrict__ outs,
                                                 float* __restrict__ last_h,
                                                 _Float16* __restrict__ h16c, int t) {
    __shared__ _Float16 xp[90 * 64];                // 11520 B, 5x18 x-patch
    __shared__ __align__(16) _Float16 uni[48 * 320];// 30720 B: f1 patch then warped tile
    __shared__ int   goff[240][4];                  // 3840 B
    __shared__ float gwgt[240][4];                  // 3840 B
    const int tid = threadIdx.x;
    const int wv = tid >> 6, ln = tid & 63;
    const int lm = ln & 15, q = ln >> 4;
    const int b  = blockIdx.x / 192;
    const int ti = blockIdx.x % 192;
    const int y0 = (ti / 6) * 3, x0 = (ti % 6) * 16;

    // phase -1: prefetch prev-h (consumed only in epilogue; hides HBM latency)
    float hp[3][4];
    #pragma unroll
    for (int nn = 0; nn < 3; nn++) {
        const int pos = (y0 + nn) * WW + x0 + lm;
        #pragma unroll
        for (int r = 0; r < 4; r++) {
            const int c = wv * 16 + q * 4 + r;
            hp[nn][r] = (t > 0) ? outs[(((size_t)b * TT + (t - 1)) * 64 + c) * HWSZ + pos] : 0.0f;
        }
    }

    // phase 0a: x patch rows y0-1..y0+3, cols x0-1..x0+16 (image remap quirk: t*4+b)
    const _Float16* xb = x16 + (size_t)(t * BB + b) * HWSZ * 64;
    for (int m = tid; m < 720; m += 256) {
        const int p = m >> 3, c = m & 7;
        const int pr = p / 18, pc = p % 18;
        const int gy = y0 - 1 + pr, gx = x0 - 1 + pc;
        half8 v = {};
        if (gy >= 0 && gy < HH && gx >= 0 && gx < WW)
            v = *(const half8*)(xb + (size_t)(gy * WW + gx) * 64 + c * 8);
        *(half8*)(&xp[p * 64 + ((c * 8) ^ ((p & 7) << 3))]) = v;
    }
    // phase 0b: f1 patch rows y0-2..y0+4, cols x0-2..x0+17, stride 40 halfs
    const _Float16* fb = f116 + (size_t)b * HWSZ * 32;
    for (int m = tid; m < 560; m += 256) {
        const int p = m >> 2, c = m & 3;
        const int pr = p / 20, pc = p % 20;
        const int gy = y0 - 2 + pr, gx = x0 - 2 + pc;
        half8 v = {};
        if (gy >= 0 && gy < HH && gx >= 0 && gx < WW)
            v = *(const half8*)(fb + (size_t)(gy * WW + gx) * 32 + c * 8);
        *(half8*)(&uni[p * 40 + c * 8]) = v;
    }
    __syncthreads();

    // phase 1: flows conv5x5 + in-register bilinear coeffs. wave rr<3 owns row y0+rr.
    if (wv < 3) {
        floatx4 fa = {};
        for (int tap = 0; tap < 25; tap++) {
            const int ky = tap / 5, kx = tap % 5;
            const half8 af = *(const half8*)(fw16 + (size_t)tap * 512 + ln * 8);
            const int p = (wv + ky) * 20 + lm + kx;
            const half8 bf = *(const half8*)(&uni[p * 40 + q * 8]);
            fa = __builtin_amdgcn_mfma_f32_16x16x32_f16(af, bf, fa, 0, 0, 0);
        }
        // lane (lm,q) holds flow channels 4q..4q+3 = pairs for l in {2q, 2q+1}
        #pragma unroll
        for (int l2 = 0; l2 < 2; l2++) {
            const int l = q * 2 + l2;
            if (l < LL) {
                const float f0  = -(fa[2 * l2 + 0] + flows_b[q * 4 + 2 * l2 + 0]);
                const float f1v = -(fa[2 * l2 + 1] + flows_b[q * 4 + 2 * l2 + 1]);
                const int yg = y0 + wv, xg = x0 + lm;
                const float nx = 2.0f * ((float)xg + f0)  / (float)(WW - 1) - 1.0f;
                const float ny = 2.0f * ((float)yg + f1v) / (float)(HH - 1) - 1.0f;
                const float fx = (nx + 1.0f) * (WW * 0.5f) - 0.5f;
                const float fy = (ny + 1.0f) * (HH * 0.5f) - 0.5f;
                const float x0f = floorf(fx), y0f = floorf(fy);
                const float wx = fx - x0f, wy = fy - y0f;
                const int xi0 = (int)x0f, yi0 = (int)y0f;
                const int idx = (wv * 16 + lm) * 5 + l;
                #pragma unroll
                for (int k = 0; k < 4; k++) {
                    const int yi = yi0 + (k >> 1);
                    const int xi = xi0 + (k & 1);
                    const bool ok = (xi >= 0 && xi < WW && yi >= 0 && yi < HH);
                    const int yc = min(max(yi, 0), HH - 1);
                    const int xc = min(max(xi, 0), WW - 1);
                    goff[idx][k] = yc * WW + xc;
                    const float wk = ((k & 1) ? wx : 1.0f - wx) * ((k >> 1) ? wy : 1.0f - wy);
                    gwgt[idx][k] = ok ? wk : 0.0f;
                }
            }
        }
    }
    __syncthreads();

    // phase 2: gather warped tile [pos48][l*64+ch] into uni (f1 patch now dead)
    const _Float16* hb = h16p + (size_t)b * HWSZ * 64;
    for (int m = tid; m < 1920; m += 256) {
        const int pl = m >> 3, c = m & 7;
        const int pp = pl / 5, l = pl % 5;
        const half8 v0 = *(const half8*)(hb + (size_t)goff[pl][0] * 64 + c * 8);
        const half8 v1 = *(const half8*)(hb + (size_t)goff[pl][1] * 64 + c * 8);
        const half8 v2 = *(const half8*)(hb + (size_t)goff[pl][2] * 64 + c * 8);
        const half8 v3 = *(const half8*)(hb + (size_t)goff[pl][3] * 64 + c * 8);
        const float w0 = gwgt[pl][0], w1 = gwgt[pl][1], w2 = gwgt[pl][2], w3 = gwgt[pl][3];
        half8 o;
        #pragma unroll
        for (int j = 0; j < 8; j++)
            o[j] = (_Float16)((float)v0[j] * w0 + (float)v1[j] * w1
                            + (float)v2[j] * w2 + (float)v3[j] * w3);
        *(half8*)(&uni[pp * 320 + ((l * 64 + c * 8) ^ ((pp & 7) << 3))]) = o;
    }
    __syncthreads();

    // phase 3: main MFMA
    floatx4 aR[3], aU[3], aIM[3], aHM[3];
    #pragma unroll
    for (int nn = 0; nn < 3; nn++)
        #pragma unroll
        for (int r = 0; r < 4; r++) {
            const int c = wv * 16 + q * 4 + r;
            aR[nn][r]  = i2h_b[c]      + ret_b[c];
            aU[nn][r]  = i2h_b[64 + c] + ret_b[64 + c];
            aIM[nn][r] = i2h_b[128 + c];
            aHM[nn][r] = ret_b[128 + c];
        }

    // i2h 3x3 (K=576) from x patch; packed wA16 fragments (mt = wv, wv+4, wv+8)
    for (int tap = 0; tap < 9; tap++) {
        const int ky = tap / 3, kx = tap % 3;
        #pragma unroll
        for (int h = 0; h < 2; h++) {
            const half8 ar = *(const half8*)(wA16 + (size_t)(((wv + 0) * 9 + tap) * 2 + h) * 512 + ln * 8);
            const half8 au = *(const half8*)(wA16 + (size_t)(((wv + 4) * 9 + tap) * 2 + h) * 512 + ln * 8);
            const half8 am = *(const half8*)(wA16 + (size_t)(((wv + 8) * 9 + tap) * 2 + h) * 512 + ln * 8);
            #pragma unroll
            for (int nn = 0; nn < 3; nn++) {
                const int p = (nn + ky) * 18 + lm + kx;
                const int sw = (p & 7) << 3;
                const half8 bf = *(const half8*)(&xp[p * 64 + ((h * 32 + q * 8) ^ sw)]);
                aR[nn]  = __builtin_amdgcn_mfma_f32_16x16x32_f16(ar, bf, aR[nn],  0, 0, 0);
                aU[nn]  = __builtin_amdgcn_mfma_f32_16x16x32_f16(au, bf, aU[nn],  0, 0, 0);
                aIM[nn] = __builtin_amdgcn_mfma_f32_16x16x32_f16(am, bf, aIM[nn], 0, 0, 0);
            }
        }
    }
    // h2h 1x1 (K=320) from warped LDS tile; packed rw16 fragments
    for (int s = 0; s < 10; s++) {
        const int k0 = s * 32;
        const half8 ar = *(const half8*)(rw16 + (size_t)((wv + 0) * 10 + s) * 512 + ln * 8);
        const half8 au = *(const half8*)(rw16 + (size_t)((wv + 4) * 10 + s) * 512 + ln * 8);
        const half8 am = *(const half8*)(rw16 + (size_t)((wv + 8) * 10 + s) * 512 + ln * 8);
        #pragma unroll
        for (int nn = 0; nn < 3; nn++) {
            const half8 bf = *(const half8*)(&uni[(nn * 16 + lm) * 320 + ((k0 + q * 8) ^ ((lm & 7) << 3))]);
            aR[nn]  = __builtin_amdgcn_mfma_f32_16x16x32_f16(ar, bf, aR[nn],  0, 0, 0);
            aU[nn]  = __builtin_amdgcn_mfma_f32_16x16x32_f16(au, bf, aU[nn],  0, 0, 0);
            aHM[nn] = __builtin_amdgcn_mfma_f32_16x16x32_f16(am, bf, aHM[nn], 0, 0, 0);
        }
    }

    // epilogue: GRU gates
    #pragma unroll
    for (int nn = 0; nn < 3; nn++) {
        const int pos = (y0 + nn) * WW + x0 + lm;
        half4 pk;
        #pragma unroll
        for (int r = 0; r < 4; r++) {
            const int c = wv * 16 + q * 4 + r;
            const float rg = 1.0f / (1.0f + expf(-aR[nn][r]));
            const float ug = 1.0f / (1.0f + expf(-aU[nn][r]));
            const float mg = tanhf(aIM[nn][r] + rg * aHM[nn][r]);
            const float nh = ug * hp[nn][r] + (1.0f - ug) * mg;
            outs[(((size_t)b * TT + t) * 64 + c) * HWSZ + pos] = nh;
            if (t == TT - 1) last_h[((size_t)b * 64 + c) * HWSZ + pos] = nh;
            pk[r] = (_Float16)nh;
        }
        *(half4*)(h16c + ((size_t)b * HWSZ + pos) * 64 + wv * 16 + q * 4) = pk;
    }
}

extern "C" void kernel_launch(void* const* d_in, const int* in_sizes, int n_in,
                              void* d_out, int out_size, void* d_ws, size_t ws_size,
                              hipStream_t stream) {
    const float* inputs  = (const float*)d_in[0];
    const float* i2h_w   = (const float*)d_in[1];
    const float* i2h_b   = (const float*)d_in[2];
    const float* i2f_w   = (const float*)d_in[3];
    const float* i2f_b   = (const float*)d_in[4];
    const float* h2f_w   = (const float*)d_in[5];
    const float* h2f_b   = (const float*)d_in[6];
    const float* flows_w = (const float*)d_in[7];
    const float* flows_b = (const float*)d_in[8];
    const float* ret_w   = (const float*)d_in[9];
    const float* ret_b   = (const float*)d_in[10];

    float* out = (float*)d_out;

    // workspace layout (bytes), total ~106.8 MB
    char* base = (char*)d_ws;
    _Float16* h16    = (_Float16*)base;   base += 9437184;    // 2 x (4*9216*64) f16 dbuf
    _Float16* f116   = (_Float16*)base;   base += 2359296;    // 4*9216*32 f16
    _Float16* x16    = (_Float16*)base;   base += 47185920;   // 40*9216*64 f16
    float*    f1x    = (float*)base;      base += 47185920;   // 40*9216*32 f32
    _Float16* wi16   = (_Float16*)base;   base += 102400;     // 2*25*2*512
    _Float16* wh16   = (_Float16*)base;   base += 102400;
    _Float16* wA16   = (_Float16*)base;   base += 221184;     // 12*9*2*512
    _Float16* rw16   = (_Float16*)base;   base += 122880;     // 12*10*512
    _Float16* fw16   = (_Float16*)base;   base += 25600;      // 25*512
    float* outs   = out;
    float* last_h = out + (size_t)BB * TT * 64 * HWSZ;

    hipMemsetAsync(h16, 0, 4718592, stream);   // buffer 0 = h at t=0

    prep_weights<<<1122, 256, 0, stream>>>(i2f_w, h2f_w, i2h_w, ret_w, flows_w,
                                           wi16, wh16, wA16, rw16, fw16);
    prep_x16<<<1440, 256, 0, stream>>>(inputs, x16);
    f1x_all<<<5760, 256, 0, stream>>>(x16, wi16, f1x);

    const size_t HB = (size_t)BB * HWSZ * 64;   // elements per h16 buffer
    for (int t = 0; t < TT; t++) {
        _Float16* hprev = h16 + (size_t)(t & 1) * HB;
        _Float16* hcur  = h16 + (size_t)((t + 1) & 1) * HB;
        f1h_mfma<<<1152, 256, 0, stream>>>(hprev, wh16, f1x, i2f_b, h2f_b, f116, t);
        gate_mega<<<768, 256, 0, stream>>>(x16, wA16, i2h_b, hprev, f116, fw16, flows_b,
                                           rw16, ret_b, outs, last_h, hcur, t);
    }
}

// Round 8
// 826.194 us; speedup vs baseline: 1.6254x; 1.0223x over previous
//
#include <hip/hip_runtime.h>
#include <math.h>

#define BB 4
#define TT 10
#define HH 96
#define WW 96
#define HWSZ 9216
#define LL 5

typedef _Float16 half8 __attribute__((ext_vector_type(8)));
typedef _Float16 half4 __attribute__((ext_vector_type(4)));
typedef float floatx4 __attribute__((ext_vector_type(4)));

// ---------------- prep: weights -> f16, FRAGMENT-PACKED layouts -----------------------
// All A-operands stored as [frag][lane64][8]: lane ln holds A[row=ln&15][k0+(ln>>4)*8+j]
// wi16/wh16: frag = (mt<2, tap<25, h<2)   -> off = ((mt*25+tap)*2+h)*512 + ln*8
// wA16:      frag = (mt<12, tap<9, h<2)   -> off = ((mt*9+tap)*2+h)*512 + ln*8
// rw16:      frag = (mt<12, s<10)         -> off = (mt*10+s)*512 + ln*8
// fw16:      frag = (tap<25)              -> off = tap*512 + ln*8   (co<10 live)
__global__ __launch_bounds__(256) void prep_weights(const float* __restrict__ i2f_w,
                                                    const float* __restrict__ h2f_w,
                                                    const float* __restrict__ i2h_w,
                                                    const float* __restrict__ ret_w,
                                                    const float* __restrict__ flows_w,
                                                    _Float16* __restrict__ wi16,
                                                    _Float16* __restrict__ wh16,
                                                    _Float16* __restrict__ wA16,
                                                    _Float16* __restrict__ rw16,
                                                    _Float16* __restrict__ fw16) {
    const int id = blockIdx.x * 256 + threadIdx.x;   // 0..287231
    if (id < 102400) {                               // wi16 / wh16 (5x5, 64ch, M=32)
        const int seg = id / 51200;                  // 0: wi16, 1: wh16
        const int r = id % 51200;
        const int mt = r / 25600, r2 = r % 25600;
        const int tap = r2 / 1024, r3 = r2 % 1024;
        const int h = r3 >> 9, ln = (r3 >> 3) & 63, j = r3 & 7;
        const int co = mt * 16 + (ln & 15);
        const int ci = h * 32 + ((ln >> 4) & 3) * 8 + j;
        const float v = seg ? h2f_w[(co * 64 + ci) * 25 + tap]
                            : i2f_w[(co * 64 + ci) * 25 + tap];
        (seg ? wh16 : wi16)[r] = (_Float16)v;
    } else if (id < 212992) {                        // wA16 (3x3, 64ch, M=192)
        const int r = id - 102400;                   // 0..110591
        const int mt = r / 9216, r2 = r % 9216;
        const int tap = r2 / 1024, r3 = r2 % 1024;
        const int h = r3 >> 9, ln = (r3 >> 3) & 63, j = r3 & 7;
        const int co = mt * 16 + (ln & 15);
        const int ci = h * 32 + ((ln >> 4) & 3) * 8 + j;
        wA16[r] = (_Float16)i2h_w[(co * 64 + ci) * 9 + tap];
    } else if (id < 274432) {                        // rw16 (1x1, K=320, M=192)
        const int r = id - 212992;                   // 0..61439
        const int mt = r / 5120, r2 = r % 5120;
        const int s = r2 / 512, r3 = r2 % 512;
        const int ln = r3 >> 3, j = r3 & 7;
        const int co = mt * 16 + (ln & 15);
        const int k = s * 32 + ((ln >> 4) & 3) * 8 + j;
        rw16[r] = (_Float16)ret_w[co * 320 + k];
    } else {                                         // fw16 (5x5, 32ch, M=16, 10 live)
        const int r = id - 274432;                   // 0..12799
        const int tap = r / 512, r3 = r % 512;
        const int ln = r3 >> 3, j = r3 & 7;
        const int co = ln & 15;
        const int ci = ((ln >> 4) & 3) * 8 + j;
        fw16[r] = (co < 10) ? (_Float16)flows_w[(co * 32 + ci) * 25 + tap] : (_Float16)0.0f;
    }
}

// ---------------- prep: x -> f16 channel-last x16[img][pos][ci], img flat (b*TT+t) ----
__global__ __launch_bounds__(256) void prep_x16(const float* __restrict__ x,
                                                _Float16* __restrict__ x16) {
    const int id = blockIdx.x * 256 + threadIdx.x;   // 0..368639
    const int img = id / HWSZ, pos = id % HWSZ;
    const float* src = x + (size_t)img * 64 * HWSZ + pos;
    _Float16* dst = x16 + ((size_t)img * HWSZ + pos) * 64;
    #pragma unroll
    for (int i = 0; i < 8; i++) {
        half8 v;
        #pragma unroll
        for (int j = 0; j < 8; j++)
            v[j] = (_Float16)src[(size_t)(i * 8 + j) * HWSZ];
        *(half8*)(dst + i * 8) = v;
    }
}

// ---------------- f1x: conv5x5(x_t) partials for ALL t, f32 out -----------------------
// Grid 5760 (g=t*4+b, 16x4 tile). Wave split = (tap-half, ci-half). Patch CHUNK-MAJOR
// [cq=8][slot=162] 16B units (stride%8==2 -> bank-uniform); tap loops fully unrolled
// so every ds_read address is laneBase + immediate (zero VALU).
__global__ __launch_bounds__(256) void f1x_all(const _Float16* __restrict__ x16,
                                               const _Float16* __restrict__ wi16,
                                               float* __restrict__ f1x) {
    __shared__ __align__(16) char smraw[33792];     // max(patch 8*162*16=20736, red 33792)
    _Float16* patch = (_Float16*)smraw;             // [cq*162 + pixel]*8 halfs
    float* red = (float*)smraw;                     // [(w*64+ln)*33 + slot]
    const int tid = threadIdx.x;
    const int wv = tid >> 6, ln = tid & 63;
    const int lm = ln & 15, q = ln >> 4;
    const int g  = blockIdx.x / 144;                // t*4+b
    const int ti = blockIdx.x % 144;
    const int y0 = (ti / 6) * 4, x0 = (ti % 6) * 16;
    const int tt = g >> 2, b = g & 3;
    const _Float16* src = x16 + (size_t)(b * TT + tt) * HWSZ * 64;

    for (int m = tid; m < 1280; m += 256) {
        const int p = m >> 3, c = m & 7;
        const int pr = p / 20, pc = p % 20;
        const int gy = y0 - 2 + pr, gx = x0 - 2 + pc;
        half8 v = {};
        if (gy >= 0 && gy < HH && gx >= 0 && gx < WW)
            v = *(const half8*)(src + (size_t)(gy * WW + gx) * 64 + c * 8);
        *(half8*)(&patch[(c * 162 + p) * 8]) = v;
    }
    __syncthreads();

    const int hh = wv & 1;                          // ci-half
    const _Float16* wbase = wi16 + hh * 512 + ln * 8;
    const int vb = ((hh * 4 + q) * 162 + lm) * 8;   // lane base (halfs)
    floatx4 acc[4][2] = {};
    #define FX_BODY(tap) { \
        const int ky = (tap) / 5, kx = (tap) % 5; \
        const half8 a0 = *(const half8*)(wbase + (tap) * 1024); \
        const half8 a1 = *(const half8*)(wbase + 25600 + (tap) * 1024); \
        _Pragma("unroll") \
        for (int n = 0; n < 4; n++) { \
            const half8 bf = *(const half8*)(&patch[vb + ((n + ky) * 20 + kx) * 8]); \
            acc[n][0] = __builtin_amdgcn_mfma_f32_16x16x32_f16(a0, bf, acc[n][0], 0, 0, 0); \
            acc[n][1] = __builtin_amdgcn_mfma_f32_16x16x32_f16(a1, bf, acc[n][1], 0, 0, 0); \
        } }
    if ((wv >> 1) == 0) {
        #pragma unroll
        for (int tap = 0; tap < 13; tap++) FX_BODY(tap)
    } else {
        #pragma unroll
        for (int tap = 13; tap < 25; tap++) FX_BODY(tap)
    }
    #undef FX_BODY
    __syncthreads();                                // patch reads done; smraw reusable
    #pragma unroll
    for (int n = 0; n < 4; n++)
        #pragma unroll
        for (int mt = 0; mt < 2; mt++)
            #pragma unroll
            for (int r = 0; r < 4; r++)
                red[(wv * 64 + ln) * 33 + n * 8 + mt * 4 + r] = acc[n][mt][r];
    __syncthreads();
    float o[8];
    #pragma unroll
    for (int j = 0; j < 8; j++) {
        const int s = wv * 8 + j;
        o[j] = red[(0 * 64 + ln) * 33 + s] + red[(1 * 64 + ln) * 33 + s]
             + red[(2 * 64 + ln) * 33 + s] + red[(3 * 64 + ln) * 33 + s];
    }
    const int pos = (y0 + wv) * WW + x0 + lm;
    float* op = f1x + ((size_t)g * HWSZ + pos) * 32;
    *(floatx4*)(op + q * 4)      = floatx4{o[0], o[1], o[2], o[3]};
    *(floatx4*)(op + 16 + q * 4) = floatx4{o[4], o[5], o[6], o[7]};
}

// ---------------- f1h: tanh(conv5x5(h) + f1x + biases), 16x2 tile, grid 1152 ----------
// Patch chunk-major [8][122]; unrolled taps; all-thread reduce + store epilogue.
__global__ __launch_bounds__(256) void f1h_mfma(const _Float16* __restrict__ h16p,
                                                const _Float16* __restrict__ wh16,
                                                const float* __restrict__ f1x,
                                                const float* __restrict__ bi,
                                                const float* __restrict__ bh,
                                                _Float16* __restrict__ f116, int t) {
    __shared__ __align__(16) char smraw[17408];     // max(patch 8*122*16=15616, red 17408)
    _Float16* patch = (_Float16*)smraw;             // [cq*122 + pixel]*8 halfs
    float* red = (float*)smraw;                     // [(w*64+ln)*17 + slot]
    const int tid = threadIdx.x;
    const int wv = tid >> 6, ln = tid & 63;
    const int lm = ln & 15, q = ln >> 4;
    const int b  = blockIdx.x / 288;
    const int ti = blockIdx.x % 288;
    const int y0 = (ti / 6) * 2, x0 = (ti % 6) * 16;
    const _Float16* src = h16p + (size_t)b * HWSZ * 64;

    for (int m = tid; m < 960; m += 256) {
        const int p = m >> 3, c = m & 7;
        const int pr = p / 20, pc = p % 20;
        const int gy = y0 - 2 + pr, gx = x0 - 2 + pc;
        half8 v = {};
        if (gy >= 0 && gy < HH && gx >= 0 && gx < WW)
            v = *(const half8*)(src + (size_t)(gy * WW + gx) * 64 + c * 8);
        *(half8*)(&patch[(c * 122 + p) * 8]) = v;
    }
    __syncthreads();

    const int hh = wv & 1;
    const _Float16* wbase = wh16 + hh * 512 + ln * 8;
    const int vb = ((hh * 4 + q) * 122 + lm) * 8;
    floatx4 acc[2][2] = {};
    #define FH_BODY(tap) { \
        const int ky = (tap) / 5, kx = (tap) % 5; \
        const half8 a0 = *(const half8*)(wbase + (tap) * 1024); \
        const half8 a1 = *(const half8*)(wbase + 25600 + (tap) * 1024); \
        _Pragma("unroll") \
        for (int n = 0; n < 2; n++) { \
            const half8 bf = *(const half8*)(&patch[vb + ((n + ky) * 20 + kx) * 8]); \
            acc[n][0] = __builtin_amdgcn_mfma_f32_16x16x32_f16(a0, bf, acc[n][0], 0, 0, 0); \
            acc[n][1] = __builtin_amdgcn_mfma_f32_16x16x32_f16(a1, bf, acc[n][1], 0, 0, 0); \
        } }
    if ((wv >> 1) == 0) {
        #pragma unroll
        for (int tap = 0; tap < 13; tap++) FH_BODY(tap)
    } else {
        #pragma unroll
        for (int tap = 13; tap < 25; tap++) FH_BODY(tap)
    }
    #undef FH_BODY
    __syncthreads();
    #pragma unroll
    for (int n = 0; n < 2; n++)
        #pragma unroll
        for (int mt = 0; mt < 2; mt++)
            #pragma unroll
            for (int r = 0; r < 4; r++)
                red[(wv * 64 + ln) * 17 + n * 8 + mt * 4 + r] = acc[n][mt][r];
    __syncthreads();
    float o[4];
    #pragma unroll
    for (int j = 0; j < 4; j++) {
        const int s = wv * 4 + j;
        o[j] = red[(0 * 64 + ln) * 17 + s] + red[(1 * 64 + ln) * 17 + s]
             + red[(2 * 64 + ln) * 17 + s] + red[(3 * 64 + ln) * 17 + s];
    }
    const int nn = wv >> 1, mh = wv & 1;
    const int pos = (y0 + nn) * WW + x0 + lm;
    const float* vx = f1x + ((size_t)(t * BB + b) * HWSZ + pos) * 32 + mh * 16;
    half4 pk;
    #pragma unroll
    for (int r = 0; r < 4; r++)
        pk[r] = (_Float16)tanhf(o[r] + vx[q * 4 + r] + bi[mh * 16 + q * 4 + r]
                                                     + bh[mh * 16 + q * 4 + r]);
    *(half4*)(f116 + ((size_t)b * HWSZ + pos) * 32 + mh * 16 + q * 4) = pk;
}

// ---------------- gate_mega: flows conv + warp-gather + i2h(3x3) + h2h(1x1) + GRU -----
// Grid 768; block = 16x3 tile. xp chunk-major [8][90]; warped tile chunk-major [40][50].
__global__ __launch_bounds__(256) void gate_mega(const _Float16* __restrict__ x16,
                                                 const _Float16* __restrict__ wA16,
                                                 const float* __restrict__ i2h_b,
                                                 const _Float16* __restrict__ h16p,
                                                 const _Float16* __restrict__ f116,
                                                 const _Float16* __restrict__ fw16,
                                                 const float* __restrict__ flows_b,
                                                 const _Float16* __restrict__ rw16,
                                                 const float* __restrict__ ret_b,
                                                 float* __restrict__ outs,
                                                 float* __restrict__ last_h,
                                                 _Float16* __restrict__ h16c, int t) {
    __shared__ __align__(16) _Float16 xp[8 * 90 * 8];   // 11520 B, chunk-major x-patch
    __shared__ __align__(16) _Float16 uni[40 * 50 * 8]; // 32000 B: f1 patch then warped
    __shared__ int   goff[240][4];                  // 3840 B
    __shared__ float gwgt[240][4];                  // 3840 B   (total 51200 B, 3/CU)
    const int tid = threadIdx.x;
    const int wv = tid >> 6, ln = tid & 63;
    const int lm = ln & 15, q = ln >> 4;
    const int b  = blockIdx.x / 192;
    const int ti = blockIdx.x % 192;
    const int y0 = (ti / 6) * 3, x0 = (ti % 6) * 16;

    // phase -1: prefetch prev-h (consumed only in epilogue; hides HBM latency)
    float hp[3][4];
    #pragma unroll
    for (int nn = 0; nn < 3; nn++) {
        const int pos = (y0 + nn) * WW + x0 + lm;
        #pragma unroll
        for (int r = 0; r < 4; r++) {
            const int c = wv * 16 + q * 4 + r;
            hp[nn][r] = (t > 0) ? outs[(((size_t)b * TT + (t - 1)) * 64 + c) * HWSZ + pos] : 0.0f;
        }
    }

    // phase 0a: x patch rows y0-1..y0+3, cols x0-1..x0+16 -> chunk-major (quirk: t*4+b)
    const _Float16* xb = x16 + (size_t)(t * BB + b) * HWSZ * 64;
    for (int m = tid; m < 720; m += 256) {
        const int p = m >> 3, c = m & 7;
        const int pr = p / 18, pc = p % 18;
        const int gy = y0 - 1 + pr, gx = x0 - 1 + pc;
        half8 v = {};
        if (gy >= 0 && gy < HH && gx >= 0 && gx < WW)
            v = *(const half8*)(xb + (size_t)(gy * WW + gx) * 64 + c * 8);
        *(half8*)(&xp[(c * 90 + p) * 8]) = v;
    }
    // phase 0b: f1 patch rows y0-2..y0+4, cols x0-2..x0+17, stride 40 halfs
    const _Float16* fb = f116 + (size_t)b * HWSZ * 32;
    for (int m = tid; m < 560; m += 256) {
        const int p = m >> 2, c = m & 3;
        const int pr = p / 20, pc = p % 20;
        const int gy = y0 - 2 + pr, gx = x0 - 2 + pc;
        half8 v = {};
        if (gy >= 0 && gy < HH && gx >= 0 && gx < WW)
            v = *(const half8*)(fb + (size_t)(gy * WW + gx) * 32 + c * 8);
        *(half8*)(&uni[p * 40 + c * 8]) = v;
    }
    __syncthreads();

    // phase 1: flows conv5x5 + in-register bilinear coeffs. wave rr<3 owns row y0+rr.
    if (wv < 3) {
        floatx4 fa = {};
        #pragma unroll
        for (int tap = 0; tap < 25; tap++) {
            const int ky = tap / 5, kx = tap % 5;
            const half8 af = *(const half8*)(fw16 + (size_t)tap * 512 + ln * 8);
            const int p = (wv + ky) * 20 + lm + kx;
            const half8 bf = *(const half8*)(&uni[p * 40 + q * 8]);
            fa = __builtin_amdgcn_mfma_f32_16x16x32_f16(af, bf, fa, 0, 0, 0);
        }
        // lane (lm,q) holds flow channels 4q..4q+3 = pairs for l in {2q, 2q+1}
        #pragma unroll
        for (int l2 = 0; l2 < 2; l2++) {
            const int l = q * 2 + l2;
            if (l < LL) {
                const float f0  = -(fa[2 * l2 + 0] + flows_b[q * 4 + 2 * l2 + 0]);
                const float f1v = -(fa[2 * l2 + 1] + flows_b[q * 4 + 2 * l2 + 1]);
                const int yg = y0 + wv, xg = x0 + lm;
                const float nx = 2.0f * ((float)xg + f0)  / (float)(WW - 1) - 1.0f;
                const float ny = 2.0f * ((float)yg + f1v) / (float)(HH - 1) - 1.0f;
                const float fx = (nx + 1.0f) * (WW * 0.5f) - 0.5f;
                const float fy = (ny + 1.0f) * (HH * 0.5f) - 0.5f;
                const float x0f = floorf(fx), y0f = floorf(fy);
                const float wx = fx - x0f, wy = fy - y0f;
                const int xi0 = (int)x0f, yi0 = (int)y0f;
                const int idx = (wv * 16 + lm) * 5 + l;
                #pragma unroll
                for (int k = 0; k < 4; k++) {
                    const int yi = yi0 + (k >> 1);
                    const int xi = xi0 + (k & 1);
                    const bool ok = (xi >= 0 && xi < WW && yi >= 0 && yi < HH);
                    const int yc = min(max(yi, 0), HH - 1);
                    const int xc = min(max(xi, 0), WW - 1);
                    goff[idx][k] = yc * WW + xc;
                    const float wk = ((k & 1) ? wx : 1.0f - wx) * ((k >> 1) ? wy : 1.0f - wy);
                    gwgt[idx][k] = ok ? wk : 0.0f;
                }
            }
        }
    }
    __syncthreads();

    // phase 2: gather warped tile -> chunk-major uni[(cq=l*8+c)*50 + pos48]
    const _Float16* hb = h16p + (size_t)b * HWSZ * 64;
    for (int m = tid; m < 1920; m += 256) {
        const int pl = m >> 3, c = m & 7;
        const int pp = pl / 5, l = pl % 5;
        const half8 v0 = *(const half8*)(hb + (size_t)goff[pl][0] * 64 + c * 8);
        const half8 v1 = *(const half8*)(hb + (size_t)goff[pl][1] * 64 + c * 8);
        const half8 v2 = *(const half8*)(hb + (size_t)goff[pl][2] * 64 + c * 8);
        const half8 v3 = *(const half8*)(hb + (size_t)goff[pl][3] * 64 + c * 8);
        const float w0 = gwgt[pl][0], w1 = gwgt[pl][1], w2 = gwgt[pl][2], w3 = gwgt[pl][3];
        half8 o;
        #pragma unroll
        for (int j = 0; j < 8; j++)
            o[j] = (_Float16)((float)v0[j] * w0 + (float)v1[j] * w1
                            + (float)v2[j] * w2 + (float)v3[j] * w3);
        *(half8*)(&uni[((l * 8 + c) * 50 + pp) * 8]) = o;
    }
    __syncthreads();

    // phase 3: main MFMA
    floatx4 aR[3], aU[3], aIM[3], aHM[3];
    #pragma unroll
    for (int nn = 0; nn < 3; nn++)
        #pragma unroll
        for (int r = 0; r < 4; r++) {
            const int c = wv * 16 + q * 4 + r;
            aR[nn][r]  = i2h_b[c]      + ret_b[c];
            aU[nn][r]  = i2h_b[64 + c] + ret_b[64 + c];
            aIM[nn][r] = i2h_b[128 + c];
            aHM[nn][r] = ret_b[128 + c];
        }

    // i2h 3x3 (K=576) from chunk-major x patch; packed wA16 fragments
    const int vbx = (q * 90 + lm) * 8;              // + h*2880 + P0*8
    #pragma unroll
    for (int tap = 0; tap < 9; tap++) {
        const int ky = tap / 3, kx = tap % 3;
        #pragma unroll
        for (int h = 0; h < 2; h++) {
            const half8 ar = *(const half8*)(wA16 + (size_t)(((wv + 0) * 9 + tap) * 2 + h) * 512 + ln * 8);
            const half8 au = *(const half8*)(wA16 + (size_t)(((wv + 4) * 9 + tap) * 2 + h) * 512 + ln * 8);
            const half8 am = *(const half8*)(wA16 + (size_t)(((wv + 8) * 9 + tap) * 2 + h) * 512 + ln * 8);
            #pragma unroll
            for (int nn = 0; nn < 3; nn++) {
                const half8 bf = *(const half8*)(&xp[vbx + h * 2880 + ((nn + ky) * 18 + kx) * 8]);
                aR[nn]  = __builtin_amdgcn_mfma_f32_16x16x32_f16(ar, bf, aR[nn],  0, 0, 0);
                aU[nn]  = __builtin_amdgcn_mfma_f32_16x16x32_f16(au, bf, aU[nn],  0, 0, 0);
                aIM[nn] = __builtin_amdgcn_mfma_f32_16x16x32_f16(am, bf, aIM[nn], 0, 0, 0);
            }
        }
    }
    // h2h 1x1 (K=320) from chunk-major warped tile; packed rw16 fragments
    const int vbu = (q * 50 + lm) * 8;              // + (s*200 + nn*16)*8
    #pragma unroll
    for (int s = 0; s < 10; s++) {
        const half8 ar = *(const half8*)(rw16 + (size_t)((wv + 0) * 10 + s) * 512 + ln * 8);
        const half8 au = *(const half8*)(rw16 + (size_t)((wv + 4) * 10 + s) * 512 + ln * 8);
        const half8 am = *(const half8*)(rw16 + (size_t)((wv + 8) * 10 + s) * 512 + ln * 8);
        #pragma unroll
        for (int nn = 0; nn < 3; nn++) {
            const half8 bf = *(const half8*)(&uni[vbu + (s * 200 + nn * 16) * 8]);
            aR[nn]  = __builtin_amdgcn_mfma_f32_16x16x32_f16(ar, bf, aR[nn],  0, 0, 0);
            aU[nn]  = __builtin_amdgcn_mfma_f32_16x16x32_f16(au, bf, aU[nn],  0, 0, 0);
            aHM[nn] = __builtin_amdgcn_mfma_f32_16x16x32_f16(am, bf, aHM[nn], 0, 0, 0);
        }
    }

    // epilogue: GRU gates
    #pragma unroll
    for (int nn = 0; nn < 3; nn++) {
        const int pos = (y0 + nn) * WW + x0 + lm;
        half4 pk;
        #pragma unroll
        for (int r = 0; r < 4; r++) {
            const int c = wv * 16 + q * 4 + r;
            const float rg = 1.0f / (1.0f + expf(-aR[nn][r]));
            const float ug = 1.0f / (1.0f + expf(-aU[nn][r]));
            const float mg = tanhf(aIM[nn][r] + rg * aHM[nn][r]);
            const float nh = ug * hp[nn][r] + (1.0f - ug) * mg;
            outs[(((size_t)b * TT + t) * 64 + c) * HWSZ + pos] = nh;
            if (t == TT - 1) last_h[((size_t)b * 64 + c) * HWSZ + pos] = nh;
            pk[r] = (_Float16)nh;
        }
        *(half4*)(h16c + ((size_t)b * HWSZ + pos) * 64 + wv * 16 + q * 4) = pk;
    }
}

extern "C" void kernel_launch(void* const* d_in, const int* in_sizes, int n_in,
                              void* d_out, int out_size, void* d_ws, size_t ws_size,
                              hipStream_t stream) {
    const float* inputs  = (const float*)d_in[0];
    const float* i2h_w   = (const float*)d_in[1];
    const float* i2h_b   = (const float*)d_in[2];
    const float* i2f_w   = (const float*)d_in[3];
    const float* i2f_b   = (const float*)d_in[4];
    const float* h2f_w   = (const float*)d_in[5];
    const float* h2f_b   = (const float*)d_in[6];
    const float* flows_w = (const float*)d_in[7];
    const float* flows_b = (const float*)d_in[8];
    const float* ret_w   = (const float*)d_in[9];
    const float* ret_b   = (const float*)d_in[10];

    float* out = (float*)d_out;

    // workspace layout (bytes), total ~106.8 MB
    char* base = (char*)d_ws;
    _Float16* h16    = (_Float16*)base;   base += 9437184;    // 2 x (4*9216*64) f16 dbuf
    _Float16* f116   = (_Float16*)base;   base += 2359296;    // 4*9216*32 f16
    _Float16* x16    = (_Float16*)base;   base += 47185920;   // 40*9216*64 f16
    float*    f1x    = (float*)base;      base += 47185920;   // 40*9216*32 f32
    _Float16* wi16   = (_Float16*)base;   base += 102400;     // 2*25*2*512
    _Float16* wh16   = (_Float16*)base;   base += 102400;
    _Float16* wA16   = (_Float16*)base;   base += 221184;     // 12*9*2*512
    _Float16* rw16   = (_Float16*)base;   base += 122880;     // 12*10*512
    _Float16* fw16   = (_Float16*)base;   base += 25600;      // 25*512
    float* outs   = out;
    float* last_h = out + (size_t)BB * TT * 64 * HWSZ;

    hipMemsetAsync(h16, 0, 4718592, stream);   // buffer 0 = h at t=0

    prep_weights<<<1122, 256, 0, stream>>>(i2f_w, h2f_w, i2h_w, ret_w, flows_w,
                                           wi16, wh16, wA16, rw16, fw16);
    prep_x16<<<1440, 256, 0, stream>>>(inputs, x16);
    f1x_all<<<5760, 256, 0, stream>>>(x16, wi16, f1x);

    const size_t HB = (size_t)BB * HWSZ * 64;   // elements per h16 buffer
    for (int t = 0; t < TT; t++) {
        _Float16* hprev = h16 + (size_t)(t & 1) * HB;
        _Float16* hcur  = h16 + (size_t)((t + 1) & 1) * HB;
        f1h_mfma<<<1152, 256, 0, stream>>>(hprev, wh16, f1x, i2f_b, h2f_b, f116, t);
        gate_mega<<<768, 256, 0, stream>>>(x16, wA16, i2h_b, hprev, f116, fw16, flows_b,
                                           rw16, ret_b, outs, last_h, hcur, t);
    }
}